// Round 14
// baseline (159.499 us; speedup 1.0000x reference)
//
#include <hip/hip_runtime.h>
#include <math.h>

#define NS 5000
#define SS 10
#define KK 20
#define HC 102
#define NBIN 32
#define BINW 16.0f
#define NPB 20           // prep/scatter blocks: ceil(5000/256)
#define CAP 192          // per-wave candidate capacity (P(overflow) ~ 0 at R<=48)

// Wave-level LDS sync: drain LDS ops + compiler ordering. Waves own private
// LDS slices; no block barrier needed (escalation may diverge between waves).
#define WAVE_SYNC() __asm__ volatile("s_waitcnt lgkmcnt(0)" ::: "memory")

// ---------- Kernel 1: stroke records + per-block bin counts (r12 verbatim) ----------
__global__ void __launch_bounds__(256) prep_kernel(
        const float* __restrict__ cs, const float* __restrict__ ce,
        const float* __restrict__ cc, const float* __restrict__ loc,
        const float* __restrict__ color, const float* __restrict__ width,
        float* __restrict__ sdata, float4* __restrict__ ctab,
        int* __restrict__ binCntP) {
    __shared__ int4 lcnt4[NBIN*NBIN/4];          // int4 decl guarantees 16B alignment
    int* lcnt = (int*)lcnt4;
    int t = threadIdx.x;
    lcnt4[t] = make_int4(0, 0, 0, 0);
    __syncthreads();
    int i = blockIdx.x * 256 + t;
    if (i < NS) {
        float lx = loc[i*2+0], ly = loc[i*2+1];
        float sx = cs[i*2+0] + lx, sy = cs[i*2+1] + ly;
        float ex = ce[i*2+0] + lx, ey = ce[i*2+1] + ly;
        float px = cc[i*2+0] + lx, py = cc[i*2+1] + ly;
        float qx[SS], qy[SS];
        #pragma unroll
        for (int j = 0; j < SS; ++j) {
            float tt = (float)j * (1.0f / 9.0f);   // linspace(0,1,10) step in fp32
            float omt = 1.0f - tt;
            float omt2 = omt * omt, t2 = tt * tt;
            qx[j] = px + omt2 * (sx - px) + t2 * (ex - px);
            qy[j] = py + omt2 * (sy - py) + t2 * (ey - py);
            sdata[i*32 + 2*j + 0] = qx[j];
            sdata[i*32 + 2*j + 1] = qy[j];
        }
        #pragma unroll
        for (int sg = 0; sg < 9; ++sg) {
            float bx = qx[sg+1] - qx[sg], by = qy[sg+1] - qy[sg];
            sdata[i*32 + 20 + sg] = 1.0f / (bx*bx + by*by);   // full precision
        }
        sdata[i*32 + 29] = 0.0f; sdata[i*32 + 30] = 0.0f; sdata[i*32 + 31] = 0.0f;
        ctab[i] = make_float4(color[i*3+0], color[i*3+1], color[i*3+2], width[i]);
        int b0 = min(max((int)(lx * (1.0f/BINW)), 0), NBIN-1);
        int b1 = min(max((int)(ly * (1.0f/BINW)), 0), NBIN-1);
        atomicAdd(&lcnt[b0*NBIN + b1], 1);
    }
    __syncthreads();
    ((int4*)binCntP)[blockIdx.x * 256 + t] = lcnt4[t];
}

// ---------- Kernel 2: redundant per-block scan + CSR scatter (r12 verbatim) ----------
__global__ void __launch_bounds__(256) scatter_kernel(
        const float* __restrict__ loc, const int* __restrict__ binCntP,
        int* __restrict__ binStart, float2* __restrict__ sxy, int* __restrict__ sid) {
    __shared__ int fill[NBIN*NBIN];
    __shared__ int wsum[4];
    int t = threadIdx.x, lane = t & 63, w = t >> 6;
    int mb = blockIdx.x;
    int4 tot = make_int4(0,0,0,0), bel = make_int4(0,0,0,0);
    for (int b = 0; b < NPB; ++b) {
        int4 v = ((const int4*)binCntP)[b * 256 + t];
        tot.x += v.x; tot.y += v.y; tot.z += v.z; tot.w += v.w;
        if (b < mb) { bel.x += v.x; bel.y += v.y; bel.z += v.z; bel.w += v.w; }
    }
    int s0 = tot.x, s1 = s0 + tot.y, s2 = s1 + tot.z, s3 = s2 + tot.w;
    int x = s3;
    #pragma unroll
    for (int off = 1; off < 64; off <<= 1) {
        int y = __shfl_up(x, off, 64);
        if (lane >= off) x += y;
    }
    if (lane == 63) wsum[w] = x;
    __syncthreads();
    int woff = 0;
    #pragma unroll
    for (int i = 0; i < 4; ++i) woff += (i < w) ? wsum[i] : 0;
    int texcl = woff + x - s3;           // exclusive prefix of this thread's 4 bins
    fill[4*t+0] = texcl      + bel.x;
    fill[4*t+1] = texcl + s0 + bel.y;
    fill[4*t+2] = texcl + s1 + bel.z;
    fill[4*t+3] = texcl + s2 + bel.w;
    if (mb == 0) {                       // publish global scan for topk
        binStart[4*t+1] = texcl + s0;
        binStart[4*t+2] = texcl + s1;
        binStart[4*t+3] = texcl + s2;
        binStart[4*t+4] = texcl + s3;
        if (t == 0) binStart[0] = 0;
    }
    __syncthreads();
    int i = mb * 256 + t;
    if (i < NS) {
        float l0 = loc[i*2+0], l1 = loc[i*2+1];
        int b0 = min(max((int)(l0 * (1.0f/BINW)), 0), NBIN-1);
        int b1 = min(max((int)(l1 * (1.0f/BINW)), 0), NBIN-1);
        int pos = atomicAdd(&fill[b0*NBIN + b1], 1);
        sxy[pos] = make_float2(l0, l1);
        sid[pos] = i;
    }
}

// ---------- Kernel 3: per-cell top-20 (r12 verbatim: exact, == jax.lax.top_k) ----------
__global__ void __launch_bounds__(256) topk_kernel(const float* __restrict__ loc,
                                                   const float* __restrict__ width,
                                                   const float2* __restrict__ sxy,
                                                   const int* __restrict__ sid,
                                                   const int* __restrict__ binStart,
                                                   int* __restrict__ idcs,
                                                   float* __restrict__ wk) {
    __shared__ unsigned long long sk[4][CAP];
    int w = threadIdx.x >> 6, lane = threadIdx.x & 63;
    int cell = blockIdx.x * 4 + w;                 // grid covers exactly HC*HC
    int ci = cell / HC, cj = cell - ci * HC;
    const float dc = 512.0f / 101.0f;              // linspace(0,512,102) step in fp32
    float c0 = (float)ci * dc;
    float c1 = (float)cj * dc;
    unsigned long long below = (1ull << lane) - 1ull;

    float R = 30.0f;                               // interior E[cnt] ~ 54
    int cnt = 0;
    for (int attempt = 0; attempt < 5; ++attempt) {
        float R2 = R * R;
        int base = 0;
        int by0 = max((int)((c0 - R) * (1.0f/BINW)), 0);
        int by1 = min((int)((c0 + R) * (1.0f/BINW)), NBIN-1);
        int bx0 = max((int)((c1 - R) * (1.0f/BINW)), 0);
        int bx1 = min((int)((c1 + R) * (1.0f/BINW)), NBIN-1);
        for (int by = by0; by <= by1; ++by) {
            int s = binStart[by*NBIN + bx0];
            int e = binStart[by*NBIN + bx1 + 1];   // bins in a row are contiguous
            for (int t0 = s; t0 < e; t0 += 64) {
                int t = t0 + lane;
                int tc = min(t, e - 1);
                float2 p = sxy[tc];
                float dx = c0 - p.x, dy = c1 - p.y;
                float d = dx*dx + dy*dy;
                bool pred = (t < e) && (d < R2);
                unsigned long long mask = __ballot(pred);
                int pos = base + __popcll(mask & below);
                if (pred && pos < CAP)
                    sk[w][pos] = ((unsigned long long)__float_as_uint(d) << 32)
                               | (unsigned int)sid[tc];
                base += __popcll(mask);
            }
        }
        cnt = base;
        if (cnt >= KK) break;                      // includes overflow -> fallback below
        R *= 1.6f;
    }
    WAVE_SYNC();

    if (cnt >= KK && cnt <= CAP) {
        if (cnt <= 64) {
            unsigned long long k0 = (lane < cnt) ? sk[w][lane] : ~0ull;
            int r0 = 0;
            int j = 0;
            #pragma unroll 1
            for (; j + 4 <= cnt; j += 4) {
                unsigned long long a = sk[w][j],   b = sk[w][j+1];
                unsigned long long c = sk[w][j+2], d = sk[w][j+3];
                r0 += (int)(a < k0) + (int)(b < k0) + (int)(c < k0) + (int)(d < k0);
            }
            for (; j < cnt; ++j) r0 += (int)(sk[w][j] < k0);
            if (r0 < KK && lane < cnt) {
                int idx = (int)(unsigned int)(k0 & 0xffffffffull);
                idcs[cell*KK + r0] = idx;
                wk[cell*KK + r0]   = width[idx];
            }
        } else {
            unsigned long long k0 = (lane       < cnt) ? sk[w][lane]       : ~0ull;
            unsigned long long k1 = (lane + 64  < cnt) ? sk[w][lane + 64]  : ~0ull;
            unsigned long long k2 = (lane + 128 < cnt) ? sk[w][lane + 128] : ~0ull;
            int r0 = 0, r1 = 0, r2 = 0;
            #pragma unroll 1
            for (int j = 0; j < cnt; ++j) {
                unsigned long long a = sk[w][j];
                r0 += (int)(a < k0); r1 += (int)(a < k1); r2 += (int)(a < k2);
            }
            if (r0 < KK && lane < cnt) {
                int idx = (int)(unsigned int)(k0 & 0xffffffffull);
                idcs[cell*KK + r0] = idx;  wk[cell*KK + r0] = width[idx];
            }
            if (r1 < KK && lane + 64 < cnt) {
                int idx = (int)(unsigned int)(k1 & 0xffffffffull);
                idcs[cell*KK + r1] = idx;  wk[cell*KK + r1] = width[idx];
            }
            if (r2 < KK && lane + 128 < cnt) {
                int idx = (int)(unsigned int)(k2 & 0xffffffffull);
                idcs[cell*KK + r2] = idx;  wk[cell*KK + r2] = width[idx];
            }
        }
    } else {
        if (lane == 0) {                 // exactness fallback (statistically never)
            float bd[KK]; int bi[KK];
            for (int k = 0; k < KK; ++k) { bd[k] = 3.4e38f; bi[k] = 0; }
            for (int n = 0; n < NS; ++n) {
                float dx = c0 - loc[n*2+0];
                float dy = c1 - loc[n*2+1];
                float d = dx*dx + dy*dy;
                if (d < bd[KK-1]) {
                    int p = KK - 1;
                    while (p > 0 && bd[p-1] > d) { bd[p] = bd[p-1]; bi[p] = bi[p-1]; --p; }
                    bd[p] = d; bi[p] = n;
                }
            }
            for (int k = 0; k < KK; ++k) {
                idcs[cell*KK + k] = bi[k];
                wk[cell*KK + k]   = width[bi[k]];
            }
        }
    }
}

// ---------- Kernel 4: render, split-k with a register budget that FITS ----------
// 128-thread block = 2 waves over ONE 8x8 pixel tile; wave h accumulates strokes
// [10h,10h+10) with the exact r12 body (numerics frozen: mink->z ulp-sensitive).
// launch_bounds(128,8) caps VGPR at 64; the body measures 48 (r12) so no spill
// (r13's (512,8) forced VGPR=32 -> 130 MB scratch traffic -> 70 us regression).
// 16 blocks/CU x 2 waves = 32 waves/CU, 2x r12's latency hiding.
// Merge via LDS rescale: proven correct in r13 (passed at bf16 floor).
__global__ void __launch_bounds__(128, 8) render_kernel(const float* __restrict__ sdata,
                                                        const float4* __restrict__ ctab,
                                                        const int* __restrict__ idcs,
                                                        const float* __restrict__ wk,
                                                        float* __restrict__ out) {
    __shared__ float part[7][64];            // half-1 partials per lane
    int tid = threadIdx.x, lane = tid & 63, h = tid >> 6;
    int x = blockIdx.x * 8 + (lane & 7);     // wave = 8x8 pixel tile
    int y = blockIdx.y * 8 + (lane >> 3);
    const float df = 512.0f / 511.0f;        // linspace(0,512,512) step in fp32
    float p0 = (float)y * df;                // H-coordinate
    float p1 = (float)x * df;                // W-coordinate
    int cy = (y * 51) >> 8;                  // floor(y*102/512), exact vs fp32 ref
    int cx = (x * 51) >> 8;
    const int* mi = idcs + (cy * HC + cx) * KK;

    // jax.image.resize linear: half-pixel centers + edge-normalized == clamped bilinear
    const float sc = 102.0f / 512.0f;        // exact in fp32
    float iny = ((float)y + 0.5f) * sc - 0.5f;
    float inx = ((float)x + 0.5f) * sc - 0.5f;
    float y0f = floorf(iny), x0f = floorf(inx);
    float fy = iny - y0f, fx = inx - x0f;
    int y0 = min(max((int)y0f, 0), HC - 1);
    int y1 = min(max((int)y0f + 1, 0), HC - 1);
    int x0 = min(max((int)x0f, 0), HC - 1);
    int x1 = min(max((int)x0f + 1, 0), HC - 1);
    const float* w00 = wk + (y0 * HC + x0) * KK;
    const float* w01 = wk + (y0 * HC + x1) * KK;
    const float* w10 = wk + (y1 * HC + x0) * KK;
    const float* w11 = wk + (y1 * HC + x1) * KK;

    float m = -INFINITY, s = 0.0f;
    float a0 = 0.0f, a1 = 0.0f, a2 = 0.0f, wa = 0.0f;
    float D = INFINITY;

    int kbeg = h * 10;
    #pragma unroll 4
    for (int kk = 0; kk < 10; ++kk) {
        int k = kbeg + kk;
        int idx = mi[k];
        const float4* sp = (const float4*)(sdata + idx * 32);
        float4 f0 = sp[0], f1 = sp[1], f2 = sp[2], f3 = sp[3], f4 = sp[4];
        float4 i0 = sp[5], i1 = sp[6], i2 = sp[7];
        float4 cw = ctab[idx];
        float qx[10] = {f0.x, f0.z, f1.x, f1.z, f2.x, f2.z, f3.x, f3.z, f4.x, f4.z};
        float qy[10] = {f0.y, f0.w, f1.y, f1.w, f2.y, f2.w, f3.y, f3.w, f4.y, f4.w};
        float iv[9]  = {i0.x, i0.y, i0.z, i0.w, i1.x, i1.y, i1.z, i1.w, i2.x};
        float mink = INFINITY;
        #pragma unroll
        for (int sg = 0; sg < 9; ++sg) {
            float ax = qx[sg], ay = qy[sg];
            float bx = qx[sg+1] - ax, by = qy[sg+1] - ay;
            float pax = p0 - ax, pay = p1 - ay;
            float dot = bx * pax + by * pay;
            float tt = dot * iv[sg];
            tt = fminf(fmaxf(tt, 0.0f), 1.0f);
            float ccx = ax + tt * bx, ccy = ay + tt * by;
            float ddx = p0 - ccx, ddy = p1 - ccy;
            float d = ddx * ddx + ddy * ddy;
            mink = fminf(mink, d);
        }
        D = fminf(D, mink);
        float z = 100000.0f / (1e-8f + mink);    // IEEE div: exponent is rounding-sensitive
        float wkv = (1.0f - fy) * ((1.0f - fx) * w00[k] + fx * w01[k])
                  +          fy * ((1.0f - fx) * w10[k] + fx * w11[k]);
        // branchless online softmax (== subtract-max softmax, exp(0)==1 exactly)
        float nm  = fmaxf(m, z);
        float scl = __expf(m - nm);              // m=-inf first iter -> 0
        float e   = __expf(z - nm);
        s  = s  * scl + e;
        a0 = a0 * scl + cw.x * e;
        a1 = a1 * scl + cw.y * e;
        a2 = a2 * scl + cw.z * e;
        wa = wa * scl + wkv  * e;
        m = nm;
    }

    if (h == 1) {                            // publish half-1 partials
        part[0][lane] = m;  part[1][lane] = s;  part[2][lane] = a0;
        part[3][lane] = a1; part[4][lane] = a2; part[5][lane] = wa;
        part[6][lane] = D;
    }
    __syncthreads();
    if (h == 0) {                            // merge + epilogue + store (r13-proven)
        float mB  = part[0][lane], sB  = part[1][lane], a0B = part[2][lane];
        float a1B = part[3][lane], a2B = part[4][lane], waB = part[5][lane];
        float DB  = part[6][lane];
        float nm = fmaxf(m, mB);
        float eA = __expf(m - nm), eB = __expf(mB - nm);
        s  = s  * eA + sB  * eB;
        a0 = a0 * eA + a0B * eB;
        a1 = a1 * eA + a1B * eB;
        a2 = a2 * eA + a2B * eB;
        wa = wa * eA + waB * eB;
        D = fminf(D, DB);

        float inv = 1.0f / s;
        float bs = wa * inv;
        float msk = 1.0f / (1.0f + __expf(-(bs - D)));   // sigmoid
        float o0 = a0 * inv * msk + (1.0f - msk) * 0.5f;
        float o1 = a1 * inv * msk + (1.0f - msk) * 0.5f;
        float o2 = a2 * inv * msk + (1.0f - msk) * 0.5f;
        int base = (y * 512 + x) * 3;
        out[base+0] = o0;
        out[base+1] = o1;
        out[base+2] = o2;
    }
}

extern "C" void kernel_launch(void* const* d_in, const int* in_sizes, int n_in,
                              void* d_out, int out_size, void* d_ws, size_t ws_size,
                              hipStream_t stream) {
    const float* cs    = (const float*)d_in[0];  // curve_s (5000,2)
    const float* ce    = (const float*)d_in[1];  // curve_e (5000,2)
    const float* cc    = (const float*)d_in[2];  // curve_c (5000,2)
    const float* color = (const float*)d_in[3];  // color   (5000,3)
    const float* loc   = (const float*)d_in[4];  // location(5000,2)
    const float* width = (const float*)d_in[5];  // width   (5000,1)
    float* out = (float*)d_out;

    char* p = (char*)d_ws;
    float*  sdata    = (float*)p;                 p += NS * 32 * sizeof(float);       // 640000
    float4* ctab     = (float4*)p;                p += NS * sizeof(float4);           // 80000
    int*    idcs     = (int*)p;                   p += (size_t)HC*HC*KK*sizeof(int);  // 832320
    float*  wk       = (float*)p;                 p += (size_t)HC*HC*KK*sizeof(float);// 832320
    int*    binCntP  = (int*)p;                   p += NPB * NBIN*NBIN * sizeof(int); // 81920
    int*    binStart = (int*)p;                   p += 4112;                          // 1025 ints + pad
    float2* sxy      = (float2*)p;                p += NS * sizeof(float2);           // 40000
    int*    sid      = (int*)p;                   /* 20000 */

    prep_kernel   <<<NPB, 256, 0, stream>>>(cs, ce, cc, loc, color, width, sdata, ctab, binCntP);
    scatter_kernel<<<NPB, 256, 0, stream>>>(loc, binCntP, binStart, sxy, sid);
    topk_kernel   <<<(HC*HC)/4, 256, 0, stream>>>(loc, width, sxy, sid, binStart, idcs, wk);
    render_kernel <<<dim3(64, 64), 128, 0, stream>>>(sdata, ctab, idcs, wk, out);
}

// Round 15
// 141.783 us; speedup vs baseline: 1.1250x; 1.1250x over previous
//
#include <hip/hip_runtime.h>
#include <math.h>

#define NS 5000
#define SS 10
#define KK 20
#define HC 102
#define NBIN 32
#define BINW 16.0f
#define NPB 20           // prep/scatter blocks: ceil(5000/256)
#define CAP 192          // per-wave candidate capacity (P(overflow) ~ 0 at R<=48)

// Wave-level LDS sync: drain LDS ops + compiler ordering. Waves own private
// LDS slices; no block barrier needed (escalation may diverge between waves).
#define WAVE_SYNC() __asm__ volatile("s_waitcnt lgkmcnt(0)" ::: "memory")

// ---------- Kernel 1: stroke records + per-block bin counts (r12 verbatim) ----------
__global__ void __launch_bounds__(256) prep_kernel(
        const float* __restrict__ cs, const float* __restrict__ ce,
        const float* __restrict__ cc, const float* __restrict__ loc,
        const float* __restrict__ color, const float* __restrict__ width,
        float* __restrict__ sdata, float4* __restrict__ ctab,
        int* __restrict__ binCntP) {
    __shared__ int4 lcnt4[NBIN*NBIN/4];          // int4 decl guarantees 16B alignment
    int* lcnt = (int*)lcnt4;
    int t = threadIdx.x;
    lcnt4[t] = make_int4(0, 0, 0, 0);
    __syncthreads();
    int i = blockIdx.x * 256 + t;
    if (i < NS) {
        float lx = loc[i*2+0], ly = loc[i*2+1];
        float sx = cs[i*2+0] + lx, sy = cs[i*2+1] + ly;
        float ex = ce[i*2+0] + lx, ey = ce[i*2+1] + ly;
        float px = cc[i*2+0] + lx, py = cc[i*2+1] + ly;
        float qx[SS], qy[SS];
        #pragma unroll
        for (int j = 0; j < SS; ++j) {
            float tt = (float)j * (1.0f / 9.0f);   // linspace(0,1,10) step in fp32
            float omt = 1.0f - tt;
            float omt2 = omt * omt, t2 = tt * tt;
            qx[j] = px + omt2 * (sx - px) + t2 * (ex - px);
            qy[j] = py + omt2 * (sy - py) + t2 * (ey - py);
            sdata[i*32 + 2*j + 0] = qx[j];
            sdata[i*32 + 2*j + 1] = qy[j];
        }
        #pragma unroll
        for (int sg = 0; sg < 9; ++sg) {
            float bx = qx[sg+1] - qx[sg], by = qy[sg+1] - qy[sg];
            sdata[i*32 + 20 + sg] = 1.0f / (bx*bx + by*by);   // full precision
        }
        sdata[i*32 + 29] = 0.0f; sdata[i*32 + 30] = 0.0f; sdata[i*32 + 31] = 0.0f;
        ctab[i] = make_float4(color[i*3+0], color[i*3+1], color[i*3+2], width[i]);
        int b0 = min(max((int)(lx * (1.0f/BINW)), 0), NBIN-1);
        int b1 = min(max((int)(ly * (1.0f/BINW)), 0), NBIN-1);
        atomicAdd(&lcnt[b0*NBIN + b1], 1);
    }
    __syncthreads();
    ((int4*)binCntP)[blockIdx.x * 256 + t] = lcnt4[t];
}

// ---------- Kernel 2: redundant per-block scan + CSR scatter (r12 verbatim) ----------
__global__ void __launch_bounds__(256) scatter_kernel(
        const float* __restrict__ loc, const int* __restrict__ binCntP,
        int* __restrict__ binStart, float2* __restrict__ sxy, int* __restrict__ sid) {
    __shared__ int fill[NBIN*NBIN];
    __shared__ int wsum[4];
    int t = threadIdx.x, lane = t & 63, w = t >> 6;
    int mb = blockIdx.x;
    int4 tot = make_int4(0,0,0,0), bel = make_int4(0,0,0,0);
    for (int b = 0; b < NPB; ++b) {
        int4 v = ((const int4*)binCntP)[b * 256 + t];
        tot.x += v.x; tot.y += v.y; tot.z += v.z; tot.w += v.w;
        if (b < mb) { bel.x += v.x; bel.y += v.y; bel.z += v.z; bel.w += v.w; }
    }
    int s0 = tot.x, s1 = s0 + tot.y, s2 = s1 + tot.z, s3 = s2 + tot.w;
    int x = s3;
    #pragma unroll
    for (int off = 1; off < 64; off <<= 1) {
        int y = __shfl_up(x, off, 64);
        if (lane >= off) x += y;
    }
    if (lane == 63) wsum[w] = x;
    __syncthreads();
    int woff = 0;
    #pragma unroll
    for (int i = 0; i < 4; ++i) woff += (i < w) ? wsum[i] : 0;
    int texcl = woff + x - s3;           // exclusive prefix of this thread's 4 bins
    fill[4*t+0] = texcl      + bel.x;
    fill[4*t+1] = texcl + s0 + bel.y;
    fill[4*t+2] = texcl + s1 + bel.z;
    fill[4*t+3] = texcl + s2 + bel.w;
    if (mb == 0) {                       // publish global scan for topk
        binStart[4*t+1] = texcl + s0;
        binStart[4*t+2] = texcl + s1;
        binStart[4*t+3] = texcl + s2;
        binStart[4*t+4] = texcl + s3;
        if (t == 0) binStart[0] = 0;
    }
    __syncthreads();
    int i = mb * 256 + t;
    if (i < NS) {
        float l0 = loc[i*2+0], l1 = loc[i*2+1];
        int b0 = min(max((int)(l0 * (1.0f/BINW)), 0), NBIN-1);
        int b1 = min(max((int)(l1 * (1.0f/BINW)), 0), NBIN-1);
        int pos = atomicAdd(&fill[b0*NBIN + b1], 1);
        sxy[pos] = make_float2(l0, l1);
        sid[pos] = i;
    }
}

// ---------- Kernel 3: per-cell top-20 (r12 verbatim: exact, == jax.lax.top_k) ----------
__global__ void __launch_bounds__(256) topk_kernel(const float* __restrict__ loc,
                                                   const float* __restrict__ width,
                                                   const float2* __restrict__ sxy,
                                                   const int* __restrict__ sid,
                                                   const int* __restrict__ binStart,
                                                   int* __restrict__ idcs,
                                                   float* __restrict__ wk) {
    __shared__ unsigned long long sk[4][CAP];
    int w = threadIdx.x >> 6, lane = threadIdx.x & 63;
    int cell = blockIdx.x * 4 + w;                 // grid covers exactly HC*HC
    int ci = cell / HC, cj = cell - ci * HC;
    const float dc = 512.0f / 101.0f;              // linspace(0,512,102) step in fp32
    float c0 = (float)ci * dc;
    float c1 = (float)cj * dc;
    unsigned long long below = (1ull << lane) - 1ull;

    float R = 30.0f;                               // interior E[cnt] ~ 54
    int cnt = 0;
    for (int attempt = 0; attempt < 5; ++attempt) {
        float R2 = R * R;
        int base = 0;
        int by0 = max((int)((c0 - R) * (1.0f/BINW)), 0);
        int by1 = min((int)((c0 + R) * (1.0f/BINW)), NBIN-1);
        int bx0 = max((int)((c1 - R) * (1.0f/BINW)), 0);
        int bx1 = min((int)((c1 + R) * (1.0f/BINW)), NBIN-1);
        for (int by = by0; by <= by1; ++by) {
            int s = binStart[by*NBIN + bx0];
            int e = binStart[by*NBIN + bx1 + 1];   // bins in a row are contiguous
            for (int t0 = s; t0 < e; t0 += 64) {
                int t = t0 + lane;
                int tc = min(t, e - 1);
                float2 p = sxy[tc];
                float dx = c0 - p.x, dy = c1 - p.y;
                float d = dx*dx + dy*dy;
                bool pred = (t < e) && (d < R2);
                unsigned long long mask = __ballot(pred);
                int pos = base + __popcll(mask & below);
                if (pred && pos < CAP)
                    sk[w][pos] = ((unsigned long long)__float_as_uint(d) << 32)
                               | (unsigned int)sid[tc];
                base += __popcll(mask);
            }
        }
        cnt = base;
        if (cnt >= KK) break;                      // includes overflow -> fallback below
        R *= 1.6f;
    }
    WAVE_SYNC();

    if (cnt >= KK && cnt <= CAP) {
        if (cnt <= 64) {
            unsigned long long k0 = (lane < cnt) ? sk[w][lane] : ~0ull;
            int r0 = 0;
            int j = 0;
            #pragma unroll 1
            for (; j + 4 <= cnt; j += 4) {
                unsigned long long a = sk[w][j],   b = sk[w][j+1];
                unsigned long long c = sk[w][j+2], d = sk[w][j+3];
                r0 += (int)(a < k0) + (int)(b < k0) + (int)(c < k0) + (int)(d < k0);
            }
            for (; j < cnt; ++j) r0 += (int)(sk[w][j] < k0);
            if (r0 < KK && lane < cnt) {
                int idx = (int)(unsigned int)(k0 & 0xffffffffull);
                idcs[cell*KK + r0] = idx;
                wk[cell*KK + r0]   = width[idx];
            }
        } else {
            unsigned long long k0 = (lane       < cnt) ? sk[w][lane]       : ~0ull;
            unsigned long long k1 = (lane + 64  < cnt) ? sk[w][lane + 64]  : ~0ull;
            unsigned long long k2 = (lane + 128 < cnt) ? sk[w][lane + 128] : ~0ull;
            int r0 = 0, r1 = 0, r2 = 0;
            #pragma unroll 1
            for (int j = 0; j < cnt; ++j) {
                unsigned long long a = sk[w][j];
                r0 += (int)(a < k0); r1 += (int)(a < k1); r2 += (int)(a < k2);
            }
            if (r0 < KK && lane < cnt) {
                int idx = (int)(unsigned int)(k0 & 0xffffffffull);
                idcs[cell*KK + r0] = idx;  wk[cell*KK + r0] = width[idx];
            }
            if (r1 < KK && lane + 64 < cnt) {
                int idx = (int)(unsigned int)(k1 & 0xffffffffull);
                idcs[cell*KK + r1] = idx;  wk[cell*KK + r1] = width[idx];
            }
            if (r2 < KK && lane + 128 < cnt) {
                int idx = (int)(unsigned int)(k2 & 0xffffffffull);
                idcs[cell*KK + r2] = idx;  wk[cell*KK + r2] = width[idx];
            }
        }
    } else {
        if (lane == 0) {                 // exactness fallback (statistically never)
            float bd[KK]; int bi[KK];
            for (int k = 0; k < KK; ++k) { bd[k] = 3.4e38f; bi[k] = 0; }
            for (int n = 0; n < NS; ++n) {
                float dx = c0 - loc[n*2+0];
                float dy = c1 - loc[n*2+1];
                float d = dx*dx + dy*dy;
                if (d < bd[KK-1]) {
                    int p = KK - 1;
                    while (p > 0 && bd[p-1] > d) { bd[p] = bd[p-1]; bi[p] = bi[p-1]; --p; }
                    bd[p] = d; bi[p] = n;
                }
            }
            for (int k = 0; k < KK; ++k) {
                idcs[cell*KK + k] = bi[k];
                wk[cell*KK + k]   = width[bi[k]];
            }
        }
    }
}

// ---------- Kernel 4: render, split-k with the cap=256/w register model ----------
// r13 (512,8) and r14 (128,8) both produced VGPR=32 + massive scratch: the
// allocator behaves as cap = 256/w arch-VGPRs per wave (unified-file split).
// Body needs 48 (measured, r12). (128,5) -> cap 51 -> expect 48, no spill,
// 5 waves/EU = 20 waves/CU (vs r12's 16), and split-k halves each wave's
// serial k-chain. Numerics of body+merge proven in r12/r13/r14 (bf16 floor).
__global__ void __launch_bounds__(128, 5) render_kernel(const float* __restrict__ sdata,
                                                        const float4* __restrict__ ctab,
                                                        const int* __restrict__ idcs,
                                                        const float* __restrict__ wk,
                                                        float* __restrict__ out) {
    __shared__ float part[7][64];            // half-1 partials per lane
    int tid = threadIdx.x, lane = tid & 63, h = tid >> 6;
    int x = blockIdx.x * 8 + (lane & 7);     // wave = 8x8 pixel tile
    int y = blockIdx.y * 8 + (lane >> 3);
    const float df = 512.0f / 511.0f;        // linspace(0,512,512) step in fp32
    float p0 = (float)y * df;                // H-coordinate
    float p1 = (float)x * df;                // W-coordinate
    int cy = (y * 51) >> 8;                  // floor(y*102/512), exact vs fp32 ref
    int cx = (x * 51) >> 8;
    const int* mi = idcs + (cy * HC + cx) * KK;

    // jax.image.resize linear: half-pixel centers + edge-normalized == clamped bilinear
    const float sc = 102.0f / 512.0f;        // exact in fp32
    float iny = ((float)y + 0.5f) * sc - 0.5f;
    float inx = ((float)x + 0.5f) * sc - 0.5f;
    float y0f = floorf(iny), x0f = floorf(inx);
    float fy = iny - y0f, fx = inx - x0f;
    int y0 = min(max((int)y0f, 0), HC - 1);
    int y1 = min(max((int)y0f + 1, 0), HC - 1);
    int x0 = min(max((int)x0f, 0), HC - 1);
    int x1 = min(max((int)x0f + 1, 0), HC - 1);
    const float* w00 = wk + (y0 * HC + x0) * KK;
    const float* w01 = wk + (y0 * HC + x1) * KK;
    const float* w10 = wk + (y1 * HC + x0) * KK;
    const float* w11 = wk + (y1 * HC + x1) * KK;

    float m = -INFINITY, s = 0.0f;
    float a0 = 0.0f, a1 = 0.0f, a2 = 0.0f, wa = 0.0f;
    float D = INFINITY;

    int kbeg = h * 10;
    #pragma unroll 4
    for (int kk = 0; kk < 10; ++kk) {
        int k = kbeg + kk;
        int idx = mi[k];
        const float4* sp = (const float4*)(sdata + idx * 32);
        float4 f0 = sp[0], f1 = sp[1], f2 = sp[2], f3 = sp[3], f4 = sp[4];
        float4 i0 = sp[5], i1 = sp[6], i2 = sp[7];
        float4 cw = ctab[idx];
        float qx[10] = {f0.x, f0.z, f1.x, f1.z, f2.x, f2.z, f3.x, f3.z, f4.x, f4.z};
        float qy[10] = {f0.y, f0.w, f1.y, f1.w, f2.y, f2.w, f3.y, f3.w, f4.y, f4.w};
        float iv[9]  = {i0.x, i0.y, i0.z, i0.w, i1.x, i1.y, i1.z, i1.w, i2.x};
        float mink = INFINITY;
        #pragma unroll
        for (int sg = 0; sg < 9; ++sg) {
            float ax = qx[sg], ay = qy[sg];
            float bx = qx[sg+1] - ax, by = qy[sg+1] - ay;
            float pax = p0 - ax, pay = p1 - ay;
            float dot = bx * pax + by * pay;
            float tt = dot * iv[sg];
            tt = fminf(fmaxf(tt, 0.0f), 1.0f);
            float ccx = ax + tt * bx, ccy = ay + tt * by;
            float ddx = p0 - ccx, ddy = p1 - ccy;
            float d = ddx * ddx + ddy * ddy;
            mink = fminf(mink, d);
        }
        D = fminf(D, mink);
        float z = 100000.0f / (1e-8f + mink);    // IEEE div: exponent is rounding-sensitive
        float wkv = (1.0f - fy) * ((1.0f - fx) * w00[k] + fx * w01[k])
                  +          fy * ((1.0f - fx) * w10[k] + fx * w11[k]);
        // branchless online softmax (== subtract-max softmax, exp(0)==1 exactly)
        float nm  = fmaxf(m, z);
        float scl = __expf(m - nm);              // m=-inf first iter -> 0
        float e   = __expf(z - nm);
        s  = s  * scl + e;
        a0 = a0 * scl + cw.x * e;
        a1 = a1 * scl + cw.y * e;
        a2 = a2 * scl + cw.z * e;
        wa = wa * scl + wkv  * e;
        m = nm;
    }

    if (h == 1) {                            // publish half-1 partials
        part[0][lane] = m;  part[1][lane] = s;  part[2][lane] = a0;
        part[3][lane] = a1; part[4][lane] = a2; part[5][lane] = wa;
        part[6][lane] = D;
    }
    __syncthreads();
    if (h == 0) {                            // merge + epilogue + store (r13/r14-proven)
        float mB  = part[0][lane], sB  = part[1][lane], a0B = part[2][lane];
        float a1B = part[3][lane], a2B = part[4][lane], waB = part[5][lane];
        float DB  = part[6][lane];
        float nm = fmaxf(m, mB);
        float eA = __expf(m - nm), eB = __expf(mB - nm);
        s  = s  * eA + sB  * eB;
        a0 = a0 * eA + a0B * eB;
        a1 = a1 * eA + a1B * eB;
        a2 = a2 * eA + a2B * eB;
        wa = wa * eA + waB * eB;
        D = fminf(D, DB);

        float inv = 1.0f / s;
        float bs = wa * inv;
        float msk = 1.0f / (1.0f + __expf(-(bs - D)));   // sigmoid
        float o0 = a0 * inv * msk + (1.0f - msk) * 0.5f;
        float o1 = a1 * inv * msk + (1.0f - msk) * 0.5f;
        float o2 = a2 * inv * msk + (1.0f - msk) * 0.5f;
        int base = (y * 512 + x) * 3;
        out[base+0] = o0;
        out[base+1] = o1;
        out[base+2] = o2;
    }
}

extern "C" void kernel_launch(void* const* d_in, const int* in_sizes, int n_in,
                              void* d_out, int out_size, void* d_ws, size_t ws_size,
                              hipStream_t stream) {
    const float* cs    = (const float*)d_in[0];  // curve_s (5000,2)
    const float* ce    = (const float*)d_in[1];  // curve_e (5000,2)
    const float* cc    = (const float*)d_in[2];  // curve_c (5000,2)
    const float* color = (const float*)d_in[3];  // color   (5000,3)
    const float* loc   = (const float*)d_in[4];  // location(5000,2)
    const float* width = (const float*)d_in[5];  // width   (5000,1)
    float* out = (float*)d_out;

    char* p = (char*)d_ws;
    float*  sdata    = (float*)p;                 p += NS * 32 * sizeof(float);       // 640000
    float4* ctab     = (float4*)p;                p += NS * sizeof(float4);           // 80000
    int*    idcs     = (int*)p;                   p += (size_t)HC*HC*KK*sizeof(int);  // 832320
    float*  wk       = (float*)p;                 p += (size_t)HC*HC*KK*sizeof(float);// 832320
    int*    binCntP  = (int*)p;                   p += NPB * NBIN*NBIN * sizeof(int); // 81920
    int*    binStart = (int*)p;                   p += 4112;                          // 1025 ints + pad
    float2* sxy      = (float2*)p;                p += NS * sizeof(float2);           // 40000
    int*    sid      = (int*)p;                   /* 20000 */

    prep_kernel   <<<NPB, 256, 0, stream>>>(cs, ce, cc, loc, color, width, sdata, ctab, binCntP);
    scatter_kernel<<<NPB, 256, 0, stream>>>(loc, binCntP, binStart, sxy, sid);
    topk_kernel   <<<(HC*HC)/4, 256, 0, stream>>>(loc, width, sxy, sid, binStart, idcs, wk);
    render_kernel <<<dim3(64, 64), 128, 0, stream>>>(sdata, ctab, idcs, wk, out);
}

// Round 16
// 135.699 us; speedup vs baseline: 1.1754x; 1.0448x over previous
//
#include <hip/hip_runtime.h>
#include <math.h>

#define NS 5000
#define SS 10
#define KK 20
#define HC 102
#define NBIN 32
#define BINW 16.0f
#define NPB 20           // prep/scatter blocks: ceil(5000/256)
#define CAP 192          // per-wave candidate capacity (P(overflow) ~ 0 at R<=48)

// Wave-level LDS sync: drain LDS ops + compiler ordering. Waves own private
// LDS slices; no block barrier needed (escalation may diverge between waves).
#define WAVE_SYNC() __asm__ volatile("s_waitcnt lgkmcnt(0)" ::: "memory")

// ---------- Kernel 1: stroke records + per-block bin counts (r12 verbatim) ----------
__global__ void __launch_bounds__(256) prep_kernel(
        const float* __restrict__ cs, const float* __restrict__ ce,
        const float* __restrict__ cc, const float* __restrict__ loc,
        const float* __restrict__ color, const float* __restrict__ width,
        float* __restrict__ sdata, float4* __restrict__ ctab,
        int* __restrict__ binCntP) {
    __shared__ int4 lcnt4[NBIN*NBIN/4];          // int4 decl guarantees 16B alignment
    int* lcnt = (int*)lcnt4;
    int t = threadIdx.x;
    lcnt4[t] = make_int4(0, 0, 0, 0);
    __syncthreads();
    int i = blockIdx.x * 256 + t;
    if (i < NS) {
        float lx = loc[i*2+0], ly = loc[i*2+1];
        float sx = cs[i*2+0] + lx, sy = cs[i*2+1] + ly;
        float ex = ce[i*2+0] + lx, ey = ce[i*2+1] + ly;
        float px = cc[i*2+0] + lx, py = cc[i*2+1] + ly;
        float qx[SS], qy[SS];
        #pragma unroll
        for (int j = 0; j < SS; ++j) {
            float tt = (float)j * (1.0f / 9.0f);   // linspace(0,1,10) step in fp32
            float omt = 1.0f - tt;
            float omt2 = omt * omt, t2 = tt * tt;
            qx[j] = px + omt2 * (sx - px) + t2 * (ex - px);
            qy[j] = py + omt2 * (sy - py) + t2 * (ey - py);
            sdata[i*32 + 2*j + 0] = qx[j];
            sdata[i*32 + 2*j + 1] = qy[j];
        }
        #pragma unroll
        for (int sg = 0; sg < 9; ++sg) {
            float bx = qx[sg+1] - qx[sg], by = qy[sg+1] - qy[sg];
            sdata[i*32 + 20 + sg] = 1.0f / (bx*bx + by*by);   // full precision
        }
        sdata[i*32 + 29] = 0.0f; sdata[i*32 + 30] = 0.0f; sdata[i*32 + 31] = 0.0f;
        ctab[i] = make_float4(color[i*3+0], color[i*3+1], color[i*3+2], width[i]);
        int b0 = min(max((int)(lx * (1.0f/BINW)), 0), NBIN-1);
        int b1 = min(max((int)(ly * (1.0f/BINW)), 0), NBIN-1);
        atomicAdd(&lcnt[b0*NBIN + b1], 1);
    }
    __syncthreads();
    ((int4*)binCntP)[blockIdx.x * 256 + t] = lcnt4[t];
}

// ---------- Kernel 2: redundant per-block scan + CSR scatter (r12 verbatim) ----------
__global__ void __launch_bounds__(256) scatter_kernel(
        const float* __restrict__ loc, const int* __restrict__ binCntP,
        int* __restrict__ binStart, float2* __restrict__ sxy, int* __restrict__ sid) {
    __shared__ int fill[NBIN*NBIN];
    __shared__ int wsum[4];
    int t = threadIdx.x, lane = t & 63, w = t >> 6;
    int mb = blockIdx.x;
    int4 tot = make_int4(0,0,0,0), bel = make_int4(0,0,0,0);
    for (int b = 0; b < NPB; ++b) {
        int4 v = ((const int4*)binCntP)[b * 256 + t];
        tot.x += v.x; tot.y += v.y; tot.z += v.z; tot.w += v.w;
        if (b < mb) { bel.x += v.x; bel.y += v.y; bel.z += v.z; bel.w += v.w; }
    }
    int s0 = tot.x, s1 = s0 + tot.y, s2 = s1 + tot.z, s3 = s2 + tot.w;
    int x = s3;
    #pragma unroll
    for (int off = 1; off < 64; off <<= 1) {
        int y = __shfl_up(x, off, 64);
        if (lane >= off) x += y;
    }
    if (lane == 63) wsum[w] = x;
    __syncthreads();
    int woff = 0;
    #pragma unroll
    for (int i = 0; i < 4; ++i) woff += (i < w) ? wsum[i] : 0;
    int texcl = woff + x - s3;           // exclusive prefix of this thread's 4 bins
    fill[4*t+0] = texcl      + bel.x;
    fill[4*t+1] = texcl + s0 + bel.y;
    fill[4*t+2] = texcl + s1 + bel.z;
    fill[4*t+3] = texcl + s2 + bel.w;
    if (mb == 0) {                       // publish global scan for topk
        binStart[4*t+1] = texcl + s0;
        binStart[4*t+2] = texcl + s1;
        binStart[4*t+3] = texcl + s2;
        binStart[4*t+4] = texcl + s3;
        if (t == 0) binStart[0] = 0;
    }
    __syncthreads();
    int i = mb * 256 + t;
    if (i < NS) {
        float l0 = loc[i*2+0], l1 = loc[i*2+1];
        int b0 = min(max((int)(l0 * (1.0f/BINW)), 0), NBIN-1);
        int b1 = min(max((int)(l1 * (1.0f/BINW)), 0), NBIN-1);
        int pos = atomicAdd(&fill[b0*NBIN + b1], 1);
        sxy[pos] = make_float2(l0, l1);
        sid[pos] = i;
    }
}

// ---------- Kernel 3: per-cell top-20 (r12 verbatim: exact, == jax.lax.top_k) ----------
__global__ void __launch_bounds__(256) topk_kernel(const float* __restrict__ loc,
                                                   const float* __restrict__ width,
                                                   const float2* __restrict__ sxy,
                                                   const int* __restrict__ sid,
                                                   const int* __restrict__ binStart,
                                                   int* __restrict__ idcs,
                                                   float* __restrict__ wk) {
    __shared__ unsigned long long sk[4][CAP];
    int w = threadIdx.x >> 6, lane = threadIdx.x & 63;
    int cell = blockIdx.x * 4 + w;                 // grid covers exactly HC*HC
    int ci = cell / HC, cj = cell - ci * HC;
    const float dc = 512.0f / 101.0f;              // linspace(0,512,102) step in fp32
    float c0 = (float)ci * dc;
    float c1 = (float)cj * dc;
    unsigned long long below = (1ull << lane) - 1ull;

    float R = 30.0f;                               // interior E[cnt] ~ 54
    int cnt = 0;
    for (int attempt = 0; attempt < 5; ++attempt) {
        float R2 = R * R;
        int base = 0;
        int by0 = max((int)((c0 - R) * (1.0f/BINW)), 0);
        int by1 = min((int)((c0 + R) * (1.0f/BINW)), NBIN-1);
        int bx0 = max((int)((c1 - R) * (1.0f/BINW)), 0);
        int bx1 = min((int)((c1 + R) * (1.0f/BINW)), NBIN-1);
        for (int by = by0; by <= by1; ++by) {
            int s = binStart[by*NBIN + bx0];
            int e = binStart[by*NBIN + bx1 + 1];   // bins in a row are contiguous
            for (int t0 = s; t0 < e; t0 += 64) {
                int t = t0 + lane;
                int tc = min(t, e - 1);
                float2 p = sxy[tc];
                float dx = c0 - p.x, dy = c1 - p.y;
                float d = dx*dx + dy*dy;
                bool pred = (t < e) && (d < R2);
                unsigned long long mask = __ballot(pred);
                int pos = base + __popcll(mask & below);
                if (pred && pos < CAP)
                    sk[w][pos] = ((unsigned long long)__float_as_uint(d) << 32)
                               | (unsigned int)sid[tc];
                base += __popcll(mask);
            }
        }
        cnt = base;
        if (cnt >= KK) break;                      // includes overflow -> fallback below
        R *= 1.6f;
    }
    WAVE_SYNC();

    if (cnt >= KK && cnt <= CAP) {
        if (cnt <= 64) {
            unsigned long long k0 = (lane < cnt) ? sk[w][lane] : ~0ull;
            int r0 = 0;
            int j = 0;
            #pragma unroll 1
            for (; j + 4 <= cnt; j += 4) {
                unsigned long long a = sk[w][j],   b = sk[w][j+1];
                unsigned long long c = sk[w][j+2], d = sk[w][j+3];
                r0 += (int)(a < k0) + (int)(b < k0) + (int)(c < k0) + (int)(d < k0);
            }
            for (; j < cnt; ++j) r0 += (int)(sk[w][j] < k0);
            if (r0 < KK && lane < cnt) {
                int idx = (int)(unsigned int)(k0 & 0xffffffffull);
                idcs[cell*KK + r0] = idx;
                wk[cell*KK + r0]   = width[idx];
            }
        } else {
            unsigned long long k0 = (lane       < cnt) ? sk[w][lane]       : ~0ull;
            unsigned long long k1 = (lane + 64  < cnt) ? sk[w][lane + 64]  : ~0ull;
            unsigned long long k2 = (lane + 128 < cnt) ? sk[w][lane + 128] : ~0ull;
            int r0 = 0, r1 = 0, r2 = 0;
            #pragma unroll 1
            for (int j = 0; j < cnt; ++j) {
                unsigned long long a = sk[w][j];
                r0 += (int)(a < k0); r1 += (int)(a < k1); r2 += (int)(a < k2);
            }
            if (r0 < KK && lane < cnt) {
                int idx = (int)(unsigned int)(k0 & 0xffffffffull);
                idcs[cell*KK + r0] = idx;  wk[cell*KK + r0] = width[idx];
            }
            if (r1 < KK && lane + 64 < cnt) {
                int idx = (int)(unsigned int)(k1 & 0xffffffffull);
                idcs[cell*KK + r1] = idx;  wk[cell*KK + r1] = width[idx];
            }
            if (r2 < KK && lane + 128 < cnt) {
                int idx = (int)(unsigned int)(k2 & 0xffffffffull);
                idcs[cell*KK + r2] = idx;  wk[cell*KK + r2] = width[idx];
            }
        }
    } else {
        if (lane == 0) {                 // exactness fallback (statistically never)
            float bd[KK]; int bi[KK];
            for (int k = 0; k < KK; ++k) { bd[k] = 3.4e38f; bi[k] = 0; }
            for (int n = 0; n < NS; ++n) {
                float dx = c0 - loc[n*2+0];
                float dy = c1 - loc[n*2+1];
                float d = dx*dx + dy*dy;
                if (d < bd[KK-1]) {
                    int p = KK - 1;
                    while (p > 0 && bd[p-1] > d) { bd[p] = bd[p-1]; bi[p] = bi[p-1]; --p; }
                    bd[p] = d; bi[p] = n;
                }
            }
            for (int k = 0; k < KK; ++k) {
                idcs[cell*KK + k] = bi[k];
                wk[cell*KK + k]   = width[bi[k]];
            }
        }
    }
}

// ---------- Kernel 4: render = r12 config + wk preblend (ONE change) ----------
// r12's 8x8-tile waves, launch_bounds(256,4), unroll 4 — all proven. The single
// delta: the 4 wk gathers per k (80/pixel) move to a preamble that loads 5
// float4 per corner and blends into wv[20]. Blend expression is textually
// identical to the in-loop version (pure load reordering). sg-loop + softmax
// numerics remain frozen (mink->z is ulp-sensitive; unroll stays 4 — r9/r10's
// failure is attributed to FULL unroll changing sg-loop contraction).
__global__ void __launch_bounds__(256, 4) render_kernel(const float* __restrict__ sdata,
                                                        const float4* __restrict__ ctab,
                                                        const int* __restrict__ idcs,
                                                        const float* __restrict__ wk,
                                                        float* __restrict__ out) {
    int tt0 = threadIdx.x, lane = tt0 & 63, wq = tt0 >> 6;
    int x = blockIdx.x * 16 + ((wq & 1) << 3) + (lane & 7);   // wave = 8x8 pixel tile
    int y = blockIdx.y * 16 + ((wq >> 1) << 3) + (lane >> 3);
    const float df = 512.0f / 511.0f;        // linspace(0,512,512) step in fp32
    float p0 = (float)y * df;                // H-coordinate
    float p1 = (float)x * df;                // W-coordinate
    int cy = (y * 51) >> 8;                  // floor(y*102/512), exact vs fp32 ref
    int cx = (x * 51) >> 8;

    // preload all 20 stroke indices (aligned: cell*20 ints = 80 B)
    const int4* mip = (const int4*)(idcs + (cy * HC + cx) * KK);
    int4 m0 = mip[0], m1 = mip[1], m2 = mip[2], m3 = mip[3], m4 = mip[4];
    int idxs[KK] = {m0.x,m0.y,m0.z,m0.w, m1.x,m1.y,m1.z,m1.w, m2.x,m2.y,m2.z,m2.w,
                    m3.x,m3.y,m3.z,m3.w, m4.x,m4.y,m4.z,m4.w};

    // jax.image.resize linear: half-pixel centers + edge-normalized == clamped bilinear
    const float sc = 102.0f / 512.0f;        // exact in fp32
    float iny = ((float)y + 0.5f) * sc - 0.5f;
    float inx = ((float)x + 0.5f) * sc - 0.5f;
    float y0f = floorf(iny), x0f = floorf(inx);
    float fy = iny - y0f, fx = inx - x0f;
    int y0 = min(max((int)y0f, 0), HC - 1);
    int y1 = min(max((int)y0f + 1, 0), HC - 1);
    int x0 = min(max((int)x0f, 0), HC - 1);
    int x1 = min(max((int)x0f + 1, 0), HC - 1);
    const float4* q00 = (const float4*)(wk + (y0 * HC + x0) * KK);
    const float4* q01 = (const float4*)(wk + (y0 * HC + x1) * KK);
    const float4* q10 = (const float4*)(wk + (y1 * HC + x0) * KK);
    const float4* q11 = (const float4*)(wk + (y1 * HC + x1) * KK);

    // preblend widths: expression textually identical to the in-loop wkv
    float wv[KK];
    #pragma unroll
    for (int r = 0; r < 5; ++r) {
        float4 a = q00[r], b = q01[r], c = q10[r], d = q11[r];
        wv[4*r+0] = (1.0f - fy) * ((1.0f - fx) * a.x + fx * b.x)
                  +          fy * ((1.0f - fx) * c.x + fx * d.x);
        wv[4*r+1] = (1.0f - fy) * ((1.0f - fx) * a.y + fx * b.y)
                  +          fy * ((1.0f - fx) * c.y + fx * d.y);
        wv[4*r+2] = (1.0f - fy) * ((1.0f - fx) * a.z + fx * b.z)
                  +          fy * ((1.0f - fx) * c.z + fx * d.z);
        wv[4*r+3] = (1.0f - fy) * ((1.0f - fx) * a.w + fx * b.w)
                  +          fy * ((1.0f - fx) * c.w + fx * d.w);
    }

    float m = -INFINITY, s = 0.0f;
    float a0 = 0.0f, a1 = 0.0f, a2 = 0.0f, wa = 0.0f;
    float D = INFINITY;

    #pragma unroll 4
    for (int k = 0; k < KK; ++k) {
        const float4* sp = (const float4*)(sdata + idxs[k] * 32);
        float4 f0 = sp[0], f1 = sp[1], f2 = sp[2], f3 = sp[3], f4 = sp[4];
        float4 i0 = sp[5], i1 = sp[6], i2 = sp[7];
        float4 cw = ctab[idxs[k]];
        float qx[10] = {f0.x, f0.z, f1.x, f1.z, f2.x, f2.z, f3.x, f3.z, f4.x, f4.z};
        float qy[10] = {f0.y, f0.w, f1.y, f1.w, f2.y, f2.w, f3.y, f3.w, f4.y, f4.w};
        float iv[9]  = {i0.x, i0.y, i0.z, i0.w, i1.x, i1.y, i1.z, i1.w, i2.x};
        float mink = INFINITY;
        #pragma unroll
        for (int sg = 0; sg < 9; ++sg) {
            float ax = qx[sg], ay = qy[sg];
            float bx = qx[sg+1] - ax, by = qy[sg+1] - ay;
            float pax = p0 - ax, pay = p1 - ay;
            float dot = bx * pax + by * pay;
            float tt = dot * iv[sg];
            tt = fminf(fmaxf(tt, 0.0f), 1.0f);
            float ccx = ax + tt * bx, ccy = ay + tt * by;
            float ddx = p0 - ccx, ddy = p1 - ccy;
            float d = ddx * ddx + ddy * ddy;
            mink = fminf(mink, d);
        }
        D = fminf(D, mink);
        float z = 100000.0f / (1e-8f + mink);    // IEEE div: exponent is rounding-sensitive
        // branchless online softmax (== subtract-max softmax, exp(0)==1 exactly)
        float nm  = fmaxf(m, z);
        float scl = __expf(m - nm);              // m=-inf first iter -> 0
        float e   = __expf(z - nm);
        s  = s  * scl + e;
        a0 = a0 * scl + cw.x * e;
        a1 = a1 * scl + cw.y * e;
        a2 = a2 * scl + cw.z * e;
        wa = wa * scl + wv[k] * e;
        m = nm;
    }
    float inv = 1.0f / s;
    float bs = wa * inv;
    float msk = 1.0f / (1.0f + __expf(-(bs - D)));   // sigmoid
    float o0 = a0 * inv * msk + (1.0f - msk) * 0.5f;
    float o1 = a1 * inv * msk + (1.0f - msk) * 0.5f;
    float o2 = a2 * inv * msk + (1.0f - msk) * 0.5f;
    int base = (y * 512 + x) * 3;
    out[base+0] = o0;
    out[base+1] = o1;
    out[base+2] = o2;
}

extern "C" void kernel_launch(void* const* d_in, const int* in_sizes, int n_in,
                              void* d_out, int out_size, void* d_ws, size_t ws_size,
                              hipStream_t stream) {
    const float* cs    = (const float*)d_in[0];  // curve_s (5000,2)
    const float* ce    = (const float*)d_in[1];  // curve_e (5000,2)
    const float* cc    = (const float*)d_in[2];  // curve_c (5000,2)
    const float* color = (const float*)d_in[3];  // color   (5000,3)
    const float* loc   = (const float*)d_in[4];  // location(5000,2)
    const float* width = (const float*)d_in[5];  // width   (5000,1)
    float* out = (float*)d_out;

    char* p = (char*)d_ws;
    float*  sdata    = (float*)p;                 p += NS * 32 * sizeof(float);       // 640000
    float4* ctab     = (float4*)p;                p += NS * sizeof(float4);           // 80000
    int*    idcs     = (int*)p;                   p += (size_t)HC*HC*KK*sizeof(int);  // 832320
    float*  wk       = (float*)p;                 p += (size_t)HC*HC*KK*sizeof(float);// 832320
    int*    binCntP  = (int*)p;                   p += NPB * NBIN*NBIN * sizeof(int); // 81920
    int*    binStart = (int*)p;                   p += 4112;                          // 1025 ints + pad
    float2* sxy      = (float2*)p;                p += NS * sizeof(float2);           // 40000
    int*    sid      = (int*)p;                   /* 20000 */

    prep_kernel   <<<NPB, 256, 0, stream>>>(cs, ce, cc, loc, color, width, sdata, ctab, binCntP);
    scatter_kernel<<<NPB, 256, 0, stream>>>(loc, binCntP, binStart, sxy, sid);
    topk_kernel   <<<(HC*HC)/4, 256, 0, stream>>>(loc, width, sxy, sid, binStart, idcs, wk);
    render_kernel <<<dim3(32, 32), 256, 0, stream>>>(sdata, ctab, idcs, wk, out);
}

// Round 17
// 129.261 us; speedup vs baseline: 1.2339x; 1.0498x over previous
//
#include <hip/hip_runtime.h>
#include <math.h>

#define NS 5000
#define SS 10
#define KK 20
#define HC 102
#define NBIN 32
#define BINW 16.0f
#define NPB 20           // prep/scatter blocks: ceil(5000/256)
#define CAP 192          // per-wave candidate capacity (P(overflow) ~ 0)

// Wave-level LDS sync: drain LDS ops + compiler ordering. Waves own private
// LDS slices; no block barrier needed (escalation may diverge between waves).
#define WAVE_SYNC() __asm__ volatile("s_waitcnt lgkmcnt(0)" ::: "memory")

// ---------- Kernel 1: stroke records + per-block bin counts (r12 verbatim) ----------
__global__ void __launch_bounds__(256) prep_kernel(
        const float* __restrict__ cs, const float* __restrict__ ce,
        const float* __restrict__ cc, const float* __restrict__ loc,
        const float* __restrict__ color, const float* __restrict__ width,
        float* __restrict__ sdata, float4* __restrict__ ctab,
        int* __restrict__ binCntP) {
    __shared__ int4 lcnt4[NBIN*NBIN/4];          // int4 decl guarantees 16B alignment
    int* lcnt = (int*)lcnt4;
    int t = threadIdx.x;
    lcnt4[t] = make_int4(0, 0, 0, 0);
    __syncthreads();
    int i = blockIdx.x * 256 + t;
    if (i < NS) {
        float lx = loc[i*2+0], ly = loc[i*2+1];
        float sx = cs[i*2+0] + lx, sy = cs[i*2+1] + ly;
        float ex = ce[i*2+0] + lx, ey = ce[i*2+1] + ly;
        float px = cc[i*2+0] + lx, py = cc[i*2+1] + ly;
        float qx[SS], qy[SS];
        #pragma unroll
        for (int j = 0; j < SS; ++j) {
            float tt = (float)j * (1.0f / 9.0f);   // linspace(0,1,10) step in fp32
            float omt = 1.0f - tt;
            float omt2 = omt * omt, t2 = tt * tt;
            qx[j] = px + omt2 * (sx - px) + t2 * (ex - px);
            qy[j] = py + omt2 * (sy - py) + t2 * (ey - py);
            sdata[i*32 + 2*j + 0] = qx[j];
            sdata[i*32 + 2*j + 1] = qy[j];
        }
        #pragma unroll
        for (int sg = 0; sg < 9; ++sg) {
            float bx = qx[sg+1] - qx[sg], by = qy[sg+1] - qy[sg];
            sdata[i*32 + 20 + sg] = 1.0f / (bx*bx + by*by);   // full precision
        }
        sdata[i*32 + 29] = 0.0f; sdata[i*32 + 30] = 0.0f; sdata[i*32 + 31] = 0.0f;
        ctab[i] = make_float4(color[i*3+0], color[i*3+1], color[i*3+2], width[i]);
        int b0 = min(max((int)(lx * (1.0f/BINW)), 0), NBIN-1);
        int b1 = min(max((int)(ly * (1.0f/BINW)), 0), NBIN-1);
        atomicAdd(&lcnt[b0*NBIN + b1], 1);
    }
    __syncthreads();
    ((int4*)binCntP)[blockIdx.x * 256 + t] = lcnt4[t];
}

// ---------- Kernel 2: redundant per-block scan + CSR scatter (r12 verbatim) ----------
__global__ void __launch_bounds__(256) scatter_kernel(
        const float* __restrict__ loc, const int* __restrict__ binCntP,
        int* __restrict__ binStart, float2* __restrict__ sxy, int* __restrict__ sid) {
    __shared__ int fill[NBIN*NBIN];
    __shared__ int wsum[4];
    int t = threadIdx.x, lane = t & 63, w = t >> 6;
    int mb = blockIdx.x;
    int4 tot = make_int4(0,0,0,0), bel = make_int4(0,0,0,0);
    for (int b = 0; b < NPB; ++b) {
        int4 v = ((const int4*)binCntP)[b * 256 + t];
        tot.x += v.x; tot.y += v.y; tot.z += v.z; tot.w += v.w;
        if (b < mb) { bel.x += v.x; bel.y += v.y; bel.z += v.z; bel.w += v.w; }
    }
    int s0 = tot.x, s1 = s0 + tot.y, s2 = s1 + tot.z, s3 = s2 + tot.w;
    int x = s3;
    #pragma unroll
    for (int off = 1; off < 64; off <<= 1) {
        int y = __shfl_up(x, off, 64);
        if (lane >= off) x += y;
    }
    if (lane == 63) wsum[w] = x;
    __syncthreads();
    int woff = 0;
    #pragma unroll
    for (int i = 0; i < 4; ++i) woff += (i < w) ? wsum[i] : 0;
    int texcl = woff + x - s3;           // exclusive prefix of this thread's 4 bins
    fill[4*t+0] = texcl      + bel.x;
    fill[4*t+1] = texcl + s0 + bel.y;
    fill[4*t+2] = texcl + s1 + bel.z;
    fill[4*t+3] = texcl + s2 + bel.w;
    if (mb == 0) {                       // publish global scan for topk
        binStart[4*t+1] = texcl + s0;
        binStart[4*t+2] = texcl + s1;
        binStart[4*t+3] = texcl + s2;
        binStart[4*t+4] = texcl + s3;
        if (t == 0) binStart[0] = 0;
    }
    __syncthreads();
    int i = mb * 256 + t;
    if (i < NS) {
        float l0 = loc[i*2+0], l1 = loc[i*2+1];
        int b0 = min(max((int)(l0 * (1.0f/BINW)), 0), NBIN-1);
        int b1 = min(max((int)(l1 * (1.0f/BINW)), 0), NBIN-1);
        int pos = atomicAdd(&fill[b0*NBIN + b1], 1);
        sxy[pos] = make_float2(l0, l1);
        sid[pos] = i;
    }
}

// ---------- Kernel 3: per-cell top-20 (r12 structure; R 30->26) ----------
// Exact for ANY R with cnt>=20 (top-20 provably inside R); escalation + serial
// fallback unchanged. R=26: E[cnt] ~ 40 (was 54) -> shorter scan + rank loops.
__global__ void __launch_bounds__(256) topk_kernel(const float* __restrict__ loc,
                                                   const float* __restrict__ width,
                                                   const float2* __restrict__ sxy,
                                                   const int* __restrict__ sid,
                                                   const int* __restrict__ binStart,
                                                   int* __restrict__ idcs,
                                                   float* __restrict__ wk) {
    __shared__ unsigned long long sk[4][CAP];
    int w = threadIdx.x >> 6, lane = threadIdx.x & 63;
    int cell = blockIdx.x * 4 + w;                 // grid covers exactly HC*HC
    int ci = cell / HC, cj = cell - ci * HC;
    const float dc = 512.0f / 101.0f;              // linspace(0,512,102) step in fp32
    float c0 = (float)ci * dc;
    float c1 = (float)cj * dc;
    unsigned long long below = (1ull << lane) - 1ull;

    float R = 26.0f;                               // E[cnt] ~ 40; P(cnt<20) ~ 2e-4
    int cnt = 0;
    for (int attempt = 0; attempt < 5; ++attempt) {
        float R2 = R * R;
        int base = 0;
        int by0 = max((int)((c0 - R) * (1.0f/BINW)), 0);
        int by1 = min((int)((c0 + R) * (1.0f/BINW)), NBIN-1);
        int bx0 = max((int)((c1 - R) * (1.0f/BINW)), 0);
        int bx1 = min((int)((c1 + R) * (1.0f/BINW)), NBIN-1);
        for (int by = by0; by <= by1; ++by) {
            int s = binStart[by*NBIN + bx0];
            int e = binStart[by*NBIN + bx1 + 1];   // bins in a row are contiguous
            for (int t0 = s; t0 < e; t0 += 64) {
                int t = t0 + lane;
                int tc = min(t, e - 1);
                float2 p = sxy[tc];
                float dx = c0 - p.x, dy = c1 - p.y;
                float d = dx*dx + dy*dy;
                bool pred = (t < e) && (d < R2);
                unsigned long long mask = __ballot(pred);
                int pos = base + __popcll(mask & below);
                if (pred && pos < CAP)
                    sk[w][pos] = ((unsigned long long)__float_as_uint(d) << 32)
                               | (unsigned int)sid[tc];
                base += __popcll(mask);
            }
        }
        cnt = base;
        if (cnt >= KK) break;                      // includes overflow -> fallback below
        R *= 1.6f;
    }
    WAVE_SYNC();

    if (cnt >= KK && cnt <= CAP) {
        if (cnt <= 64) {
            unsigned long long k0 = (lane < cnt) ? sk[w][lane] : ~0ull;
            int r0 = 0;
            int j = 0;
            #pragma unroll 1
            for (; j + 4 <= cnt; j += 4) {
                unsigned long long a = sk[w][j],   b = sk[w][j+1];
                unsigned long long c = sk[w][j+2], d = sk[w][j+3];
                r0 += (int)(a < k0) + (int)(b < k0) + (int)(c < k0) + (int)(d < k0);
            }
            for (; j < cnt; ++j) r0 += (int)(sk[w][j] < k0);
            if (r0 < KK && lane < cnt) {
                int idx = (int)(unsigned int)(k0 & 0xffffffffull);
                idcs[cell*KK + r0] = idx;
                wk[cell*KK + r0]   = width[idx];
            }
        } else {
            unsigned long long k0 = (lane       < cnt) ? sk[w][lane]       : ~0ull;
            unsigned long long k1 = (lane + 64  < cnt) ? sk[w][lane + 64]  : ~0ull;
            unsigned long long k2 = (lane + 128 < cnt) ? sk[w][lane + 128] : ~0ull;
            int r0 = 0, r1 = 0, r2 = 0;
            #pragma unroll 1
            for (int j = 0; j < cnt; ++j) {
                unsigned long long a = sk[w][j];
                r0 += (int)(a < k0); r1 += (int)(a < k1); r2 += (int)(a < k2);
            }
            if (r0 < KK && lane < cnt) {
                int idx = (int)(unsigned int)(k0 & 0xffffffffull);
                idcs[cell*KK + r0] = idx;  wk[cell*KK + r0] = width[idx];
            }
            if (r1 < KK && lane + 64 < cnt) {
                int idx = (int)(unsigned int)(k1 & 0xffffffffull);
                idcs[cell*KK + r1] = idx;  wk[cell*KK + r1] = width[idx];
            }
            if (r2 < KK && lane + 128 < cnt) {
                int idx = (int)(unsigned int)(k2 & 0xffffffffull);
                idcs[cell*KK + r2] = idx;  wk[cell*KK + r2] = width[idx];
            }
        }
    } else {
        if (lane == 0) {                 // exactness fallback (statistically never)
            float bd[KK]; int bi[KK];
            for (int k = 0; k < KK; ++k) { bd[k] = 3.4e38f; bi[k] = 0; }
            for (int n = 0; n < NS; ++n) {
                float dx = c0 - loc[n*2+0];
                float dy = c1 - loc[n*2+1];
                float d = dx*dx + dy*dy;
                if (d < bd[KK-1]) {
                    int p = KK - 1;
                    while (p > 0 && bd[p-1] > d) { bd[p] = bd[p-1]; bi[p] = bi[p-1]; --p; }
                    bd[p] = d; bi[p] = n;
                }
            }
            for (int k = 0; k < KK; ++k) {
                idcs[cell*KK + k] = bi[k];
                wk[cell*KK + k]   = width[bi[k]];
            }
        }
    }
}

// ---------- Kernel 4: render = r12 + wk preblend parked in LDS ----------
// r16 proved the preblend is numerically safe but its wv[20] register array
// spilled to scratch under runtime-k indexing (42 MB round-trip). Fix: park
// wv in LDS (runtime-indexable). Row stride 21 (gcd(21,32)=1) -> lane-row
// reads are 2 lanes/bank = conflict-free. Thread-private rows: no barrier.
// sg-loop + softmax numerics frozen (mink->z ulp-sensitive); unroll stays 4.
__global__ void __launch_bounds__(256, 4) render_kernel(const float* __restrict__ sdata,
                                                        const float4* __restrict__ ctab,
                                                        const int* __restrict__ idcs,
                                                        const float* __restrict__ wk,
                                                        float* __restrict__ out) {
    __shared__ float wvl[256][21];           // 21.5 KB; stride 21 breaks bank aliasing
    int tt0 = threadIdx.x, lane = tt0 & 63, wq = tt0 >> 6;
    int x = blockIdx.x * 16 + ((wq & 1) << 3) + (lane & 7);   // wave = 8x8 pixel tile
    int y = blockIdx.y * 16 + ((wq >> 1) << 3) + (lane >> 3);
    const float df = 512.0f / 511.0f;        // linspace(0,512,512) step in fp32
    float p0 = (float)y * df;                // H-coordinate
    float p1 = (float)x * df;                // W-coordinate
    int cy = (y * 51) >> 8;                  // floor(y*102/512), exact vs fp32 ref
    int cx = (x * 51) >> 8;

    // preload all 20 stroke indices (aligned: cell*20 ints = 80 B)
    const int4* mip = (const int4*)(idcs + (cy * HC + cx) * KK);
    int4 m0 = mip[0], m1 = mip[1], m2 = mip[2], m3 = mip[3], m4 = mip[4];
    int idxs[KK] = {m0.x,m0.y,m0.z,m0.w, m1.x,m1.y,m1.z,m1.w, m2.x,m2.y,m2.z,m2.w,
                    m3.x,m3.y,m3.z,m3.w, m4.x,m4.y,m4.z,m4.w};

    // jax.image.resize linear: half-pixel centers + edge-normalized == clamped bilinear
    const float sc = 102.0f / 512.0f;        // exact in fp32
    float iny = ((float)y + 0.5f) * sc - 0.5f;
    float inx = ((float)x + 0.5f) * sc - 0.5f;
    float y0f = floorf(iny), x0f = floorf(inx);
    float fy = iny - y0f, fx = inx - x0f;
    int y0 = min(max((int)y0f, 0), HC - 1);
    int y1 = min(max((int)y0f + 1, 0), HC - 1);
    int x0 = min(max((int)x0f, 0), HC - 1);
    int x1 = min(max((int)x0f + 1, 0), HC - 1);
    const float4* q00 = (const float4*)(wk + (y0 * HC + x0) * KK);
    const float4* q01 = (const float4*)(wk + (y0 * HC + x1) * KK);
    const float4* q10 = (const float4*)(wk + (y1 * HC + x0) * KK);
    const float4* q11 = (const float4*)(wk + (y1 * HC + x1) * KK);

    // preblend widths (expression identical to r16, which passed) -> LDS row
    #pragma unroll
    for (int r = 0; r < 5; ++r) {
        float4 a = q00[r], b = q01[r], c = q10[r], d = q11[r];
        wvl[tt0][4*r+0] = (1.0f - fy) * ((1.0f - fx) * a.x + fx * b.x)
                        +          fy * ((1.0f - fx) * c.x + fx * d.x);
        wvl[tt0][4*r+1] = (1.0f - fy) * ((1.0f - fx) * a.y + fx * b.y)
                        +          fy * ((1.0f - fx) * c.y + fx * d.y);
        wvl[tt0][4*r+2] = (1.0f - fy) * ((1.0f - fx) * a.z + fx * b.z)
                        +          fy * ((1.0f - fx) * c.z + fx * d.z);
        wvl[tt0][4*r+3] = (1.0f - fy) * ((1.0f - fx) * a.w + fx * b.w)
                        +          fy * ((1.0f - fx) * c.w + fx * d.w);
    }

    float m = -INFINITY, s = 0.0f;
    float a0 = 0.0f, a1 = 0.0f, a2 = 0.0f, wa = 0.0f;
    float D = INFINITY;

    #pragma unroll 4
    for (int k = 0; k < KK; ++k) {
        const float4* sp = (const float4*)(sdata + idxs[k] * 32);
        float4 f0 = sp[0], f1 = sp[1], f2 = sp[2], f3 = sp[3], f4 = sp[4];
        float4 i0 = sp[5], i1 = sp[6], i2 = sp[7];
        float4 cw = ctab[idxs[k]];
        float qx[10] = {f0.x, f0.z, f1.x, f1.z, f2.x, f2.z, f3.x, f3.z, f4.x, f4.z};
        float qy[10] = {f0.y, f0.w, f1.y, f1.w, f2.y, f2.w, f3.y, f3.w, f4.y, f4.w};
        float iv[9]  = {i0.x, i0.y, i0.z, i0.w, i1.x, i1.y, i1.z, i1.w, i2.x};
        float mink = INFINITY;
        #pragma unroll
        for (int sg = 0; sg < 9; ++sg) {
            float ax = qx[sg], ay = qy[sg];
            float bx = qx[sg+1] - ax, by = qy[sg+1] - ay;
            float pax = p0 - ax, pay = p1 - ay;
            float dot = bx * pax + by * pay;
            float tt = dot * iv[sg];
            tt = fminf(fmaxf(tt, 0.0f), 1.0f);
            float ccx = ax + tt * bx, ccy = ay + tt * by;
            float ddx = p0 - ccx, ddy = p1 - ccy;
            float d = ddx * ddx + ddy * ddy;
            mink = fminf(mink, d);
        }
        D = fminf(D, mink);
        float z = 100000.0f / (1e-8f + mink);    // IEEE div: exponent is rounding-sensitive
        // branchless online softmax (== subtract-max softmax, exp(0)==1 exactly)
        float nm  = fmaxf(m, z);
        float scl = __expf(m - nm);              // m=-inf first iter -> 0
        float e   = __expf(z - nm);
        s  = s  * scl + e;
        a0 = a0 * scl + cw.x * e;
        a1 = a1 * scl + cw.y * e;
        a2 = a2 * scl + cw.z * e;
        wa = wa * scl + wvl[tt0][k] * e;
        m = nm;
    }
    float inv = 1.0f / s;
    float bs = wa * inv;
    float msk = 1.0f / (1.0f + __expf(-(bs - D)));   // sigmoid
    float o0 = a0 * inv * msk + (1.0f - msk) * 0.5f;
    float o1 = a1 * inv * msk + (1.0f - msk) * 0.5f;
    float o2 = a2 * inv * msk + (1.0f - msk) * 0.5f;
    int base = (y * 512 + x) * 3;
    out[base+0] = o0;
    out[base+1] = o1;
    out[base+2] = o2;
}

extern "C" void kernel_launch(void* const* d_in, const int* in_sizes, int n_in,
                              void* d_out, int out_size, void* d_ws, size_t ws_size,
                              hipStream_t stream) {
    const float* cs    = (const float*)d_in[0];  // curve_s (5000,2)
    const float* ce    = (const float*)d_in[1];  // curve_e (5000,2)
    const float* cc    = (const float*)d_in[2];  // curve_c (5000,2)
    const float* color = (const float*)d_in[3];  // color   (5000,3)
    const float* loc   = (const float*)d_in[4];  // location(5000,2)
    const float* width = (const float*)d_in[5];  // width   (5000,1)
    float* out = (float*)d_out;

    char* p = (char*)d_ws;
    float*  sdata    = (float*)p;                 p += NS * 32 * sizeof(float);       // 640000
    float4* ctab     = (float4*)p;                p += NS * sizeof(float4);           // 80000
    int*    idcs     = (int*)p;                   p += (size_t)HC*HC*KK*sizeof(int);  // 832320
    float*  wk       = (float*)p;                 p += (size_t)HC*HC*KK*sizeof(float);// 832320
    int*    binCntP  = (int*)p;                   p += NPB * NBIN*NBIN * sizeof(int); // 81920
    int*    binStart = (int*)p;                   p += 4112;                          // 1025 ints + pad
    float2* sxy      = (float2*)p;                p += NS * sizeof(float2);           // 40000
    int*    sid      = (int*)p;                   /* 20000 */

    prep_kernel   <<<NPB, 256, 0, stream>>>(cs, ce, cc, loc, color, width, sdata, ctab, binCntP);
    scatter_kernel<<<NPB, 256, 0, stream>>>(loc, binCntP, binStart, sxy, sid);
    topk_kernel   <<<(HC*HC)/4, 256, 0, stream>>>(loc, width, sxy, sid, binStart, idcs, wk);
    render_kernel <<<dim3(32, 32), 256, 0, stream>>>(sdata, ctab, idcs, wk, out);
}

// Round 18
// 128.340 us; speedup vs baseline: 1.2428x; 1.0072x over previous
//
#include <hip/hip_runtime.h>
#include <math.h>

#define NS 5000
#define SS 10
#define KK 20
#define HC 102
#define NBIN 32
#define BINW 16.0f
#define NPB 20           // prep/scatter blocks: ceil(5000/256)
#define CAP 192          // per-wave candidate capacity (P(overflow) ~ 0)

// Wave-level LDS sync: drain LDS ops + compiler ordering. Waves own private
// LDS slices; no block barrier needed (escalation may diverge between waves).
#define WAVE_SYNC() __asm__ volatile("s_waitcnt lgkmcnt(0)" ::: "memory")

// ---------- Kernel 1: stroke records + per-block bin counts (r12 verbatim) ----------
__global__ void __launch_bounds__(256) prep_kernel(
        const float* __restrict__ cs, const float* __restrict__ ce,
        const float* __restrict__ cc, const float* __restrict__ loc,
        const float* __restrict__ color, const float* __restrict__ width,
        float* __restrict__ sdata, float4* __restrict__ ctab,
        int* __restrict__ binCntP) {
    __shared__ int4 lcnt4[NBIN*NBIN/4];          // int4 decl guarantees 16B alignment
    int* lcnt = (int*)lcnt4;
    int t = threadIdx.x;
    lcnt4[t] = make_int4(0, 0, 0, 0);
    __syncthreads();
    int i = blockIdx.x * 256 + t;
    if (i < NS) {
        float lx = loc[i*2+0], ly = loc[i*2+1];
        float sx = cs[i*2+0] + lx, sy = cs[i*2+1] + ly;
        float ex = ce[i*2+0] + lx, ey = ce[i*2+1] + ly;
        float px = cc[i*2+0] + lx, py = cc[i*2+1] + ly;
        float qx[SS], qy[SS];
        #pragma unroll
        for (int j = 0; j < SS; ++j) {
            float tt = (float)j * (1.0f / 9.0f);   // linspace(0,1,10) step in fp32
            float omt = 1.0f - tt;
            float omt2 = omt * omt, t2 = tt * tt;
            qx[j] = px + omt2 * (sx - px) + t2 * (ex - px);
            qy[j] = py + omt2 * (sy - py) + t2 * (ey - py);
            sdata[i*32 + 2*j + 0] = qx[j];
            sdata[i*32 + 2*j + 1] = qy[j];
        }
        #pragma unroll
        for (int sg = 0; sg < 9; ++sg) {
            float bx = qx[sg+1] - qx[sg], by = qy[sg+1] - qy[sg];
            sdata[i*32 + 20 + sg] = 1.0f / (bx*bx + by*by);   // full precision
        }
        sdata[i*32 + 29] = 0.0f; sdata[i*32 + 30] = 0.0f; sdata[i*32 + 31] = 0.0f;
        ctab[i] = make_float4(color[i*3+0], color[i*3+1], color[i*3+2], width[i]);
        int b0 = min(max((int)(lx * (1.0f/BINW)), 0), NBIN-1);
        int b1 = min(max((int)(ly * (1.0f/BINW)), 0), NBIN-1);
        atomicAdd(&lcnt[b0*NBIN + b1], 1);
    }
    __syncthreads();
    ((int4*)binCntP)[blockIdx.x * 256 + t] = lcnt4[t];
}

// ---------- Kernel 2: redundant per-block scan + CSR scatter (r12 verbatim) ----------
__global__ void __launch_bounds__(256) scatter_kernel(
        const float* __restrict__ loc, const int* __restrict__ binCntP,
        int* __restrict__ binStart, float2* __restrict__ sxy, int* __restrict__ sid) {
    __shared__ int fill[NBIN*NBIN];
    __shared__ int wsum[4];
    int t = threadIdx.x, lane = t & 63, w = t >> 6;
    int mb = blockIdx.x;
    int4 tot = make_int4(0,0,0,0), bel = make_int4(0,0,0,0);
    for (int b = 0; b < NPB; ++b) {
        int4 v = ((const int4*)binCntP)[b * 256 + t];
        tot.x += v.x; tot.y += v.y; tot.z += v.z; tot.w += v.w;
        if (b < mb) { bel.x += v.x; bel.y += v.y; bel.z += v.z; bel.w += v.w; }
    }
    int s0 = tot.x, s1 = s0 + tot.y, s2 = s1 + tot.z, s3 = s2 + tot.w;
    int x = s3;
    #pragma unroll
    for (int off = 1; off < 64; off <<= 1) {
        int y = __shfl_up(x, off, 64);
        if (lane >= off) x += y;
    }
    if (lane == 63) wsum[w] = x;
    __syncthreads();
    int woff = 0;
    #pragma unroll
    for (int i = 0; i < 4; ++i) woff += (i < w) ? wsum[i] : 0;
    int texcl = woff + x - s3;           // exclusive prefix of this thread's 4 bins
    fill[4*t+0] = texcl      + bel.x;
    fill[4*t+1] = texcl + s0 + bel.y;
    fill[4*t+2] = texcl + s1 + bel.z;
    fill[4*t+3] = texcl + s2 + bel.w;
    if (mb == 0) {                       // publish global scan for topk
        binStart[4*t+1] = texcl + s0;
        binStart[4*t+2] = texcl + s1;
        binStart[4*t+3] = texcl + s2;
        binStart[4*t+4] = texcl + s3;
        if (t == 0) binStart[0] = 0;
    }
    __syncthreads();
    int i = mb * 256 + t;
    if (i < NS) {
        float l0 = loc[i*2+0], l1 = loc[i*2+1];
        int b0 = min(max((int)(l0 * (1.0f/BINW)), 0), NBIN-1);
        int b1 = min(max((int)(l1 * (1.0f/BINW)), 0), NBIN-1);
        int pos = atomicAdd(&fill[b0*NBIN + b1], 1);
        sxy[pos] = make_float2(l0, l1);
        sid[pos] = i;
    }
}

// ---------- Kernel 3: per-cell top-20 (r17 verbatim: exact, R=26) ----------
__global__ void __launch_bounds__(256) topk_kernel(const float* __restrict__ loc,
                                                   const float* __restrict__ width,
                                                   const float2* __restrict__ sxy,
                                                   const int* __restrict__ sid,
                                                   const int* __restrict__ binStart,
                                                   int* __restrict__ idcs,
                                                   float* __restrict__ wk) {
    __shared__ unsigned long long sk[4][CAP];
    int w = threadIdx.x >> 6, lane = threadIdx.x & 63;
    int cell = blockIdx.x * 4 + w;                 // grid covers exactly HC*HC
    int ci = cell / HC, cj = cell - ci * HC;
    const float dc = 512.0f / 101.0f;              // linspace(0,512,102) step in fp32
    float c0 = (float)ci * dc;
    float c1 = (float)cj * dc;
    unsigned long long below = (1ull << lane) - 1ull;

    float R = 26.0f;                               // E[cnt] ~ 40; P(cnt<20) ~ 2e-4
    int cnt = 0;
    for (int attempt = 0; attempt < 5; ++attempt) {
        float R2 = R * R;
        int base = 0;
        int by0 = max((int)((c0 - R) * (1.0f/BINW)), 0);
        int by1 = min((int)((c0 + R) * (1.0f/BINW)), NBIN-1);
        int bx0 = max((int)((c1 - R) * (1.0f/BINW)), 0);
        int bx1 = min((int)((c1 + R) * (1.0f/BINW)), NBIN-1);
        for (int by = by0; by <= by1; ++by) {
            int s = binStart[by*NBIN + bx0];
            int e = binStart[by*NBIN + bx1 + 1];   // bins in a row are contiguous
            for (int t0 = s; t0 < e; t0 += 64) {
                int t = t0 + lane;
                int tc = min(t, e - 1);
                float2 p = sxy[tc];
                float dx = c0 - p.x, dy = c1 - p.y;
                float d = dx*dx + dy*dy;
                bool pred = (t < e) && (d < R2);
                unsigned long long mask = __ballot(pred);
                int pos = base + __popcll(mask & below);
                if (pred && pos < CAP)
                    sk[w][pos] = ((unsigned long long)__float_as_uint(d) << 32)
                               | (unsigned int)sid[tc];
                base += __popcll(mask);
            }
        }
        cnt = base;
        if (cnt >= KK) break;                      // includes overflow -> fallback below
        R *= 1.6f;
    }
    WAVE_SYNC();

    if (cnt >= KK && cnt <= CAP) {
        if (cnt <= 64) {
            unsigned long long k0 = (lane < cnt) ? sk[w][lane] : ~0ull;
            int r0 = 0;
            int j = 0;
            #pragma unroll 1
            for (; j + 4 <= cnt; j += 4) {
                unsigned long long a = sk[w][j],   b = sk[w][j+1];
                unsigned long long c = sk[w][j+2], d = sk[w][j+3];
                r0 += (int)(a < k0) + (int)(b < k0) + (int)(c < k0) + (int)(d < k0);
            }
            for (; j < cnt; ++j) r0 += (int)(sk[w][j] < k0);
            if (r0 < KK && lane < cnt) {
                int idx = (int)(unsigned int)(k0 & 0xffffffffull);
                idcs[cell*KK + r0] = idx;
                wk[cell*KK + r0]   = width[idx];
            }
        } else {
            unsigned long long k0 = (lane       < cnt) ? sk[w][lane]       : ~0ull;
            unsigned long long k1 = (lane + 64  < cnt) ? sk[w][lane + 64]  : ~0ull;
            unsigned long long k2 = (lane + 128 < cnt) ? sk[w][lane + 128] : ~0ull;
            int r0 = 0, r1 = 0, r2 = 0;
            #pragma unroll 1
            for (int j = 0; j < cnt; ++j) {
                unsigned long long a = sk[w][j];
                r0 += (int)(a < k0); r1 += (int)(a < k1); r2 += (int)(a < k2);
            }
            if (r0 < KK && lane < cnt) {
                int idx = (int)(unsigned int)(k0 & 0xffffffffull);
                idcs[cell*KK + r0] = idx;  wk[cell*KK + r0] = width[idx];
            }
            if (r1 < KK && lane + 64 < cnt) {
                int idx = (int)(unsigned int)(k1 & 0xffffffffull);
                idcs[cell*KK + r1] = idx;  wk[cell*KK + r1] = width[idx];
            }
            if (r2 < KK && lane + 128 < cnt) {
                int idx = (int)(unsigned int)(k2 & 0xffffffffull);
                idcs[cell*KK + r2] = idx;  wk[cell*KK + r2] = width[idx];
            }
        }
    } else {
        if (lane == 0) {                 // exactness fallback (statistically never)
            float bd[KK]; int bi[KK];
            for (int k = 0; k < KK; ++k) { bd[k] = 3.4e38f; bi[k] = 0; }
            for (int n = 0; n < NS; ++n) {
                float dx = c0 - loc[n*2+0];
                float dy = c1 - loc[n*2+1];
                float d = dx*dx + dy*dy;
                if (d < bd[KK-1]) {
                    int p = KK - 1;
                    while (p > 0 && bd[p-1] > d) { bd[p] = bd[p-1]; bi[p] = bi[p-1]; --p; }
                    bd[p] = d; bi[p] = n;
                }
            }
            for (int k = 0; k < KK; ++k) {
                idcs[cell*KK + k] = bi[k];
                wk[cell*KK + k]   = width[bi[k]];
            }
        }
    }
}

// ---------- Kernel 4: render = r17 + dual in-thread softmax accumulators ----------
// Theory: render is bound by the 20-step serial softmax dependency chain
// (m->exp->s), not loads/occupancy/divergence (r11/r15/r17 all null). Split
// the chain: even strokes -> chain A, odd -> chain B; merge with the
// r13/14/15-proven rescale (passed at bf16 floor 3x; same re-association
// class). Per-stroke body textually frozen (mink->z is ulp-sensitive).
__global__ void __launch_bounds__(256, 4) render_kernel(const float* __restrict__ sdata,
                                                        const float4* __restrict__ ctab,
                                                        const int* __restrict__ idcs,
                                                        const float* __restrict__ wk,
                                                        float* __restrict__ out) {
    __shared__ float wvl[256][21];           // 21.5 KB; stride 21 breaks bank aliasing
    int tt0 = threadIdx.x, lane = tt0 & 63, wq = tt0 >> 6;
    int x = blockIdx.x * 16 + ((wq & 1) << 3) + (lane & 7);   // wave = 8x8 pixel tile
    int y = blockIdx.y * 16 + ((wq >> 1) << 3) + (lane >> 3);
    const float df = 512.0f / 511.0f;        // linspace(0,512,512) step in fp32
    float p0 = (float)y * df;                // H-coordinate
    float p1 = (float)x * df;                // W-coordinate
    int cy = (y * 51) >> 8;                  // floor(y*102/512), exact vs fp32 ref
    int cx = (x * 51) >> 8;

    // preload all 20 stroke indices (aligned: cell*20 ints = 80 B)
    const int4* mip = (const int4*)(idcs + (cy * HC + cx) * KK);
    int4 m0 = mip[0], m1 = mip[1], m2 = mip[2], m3 = mip[3], m4 = mip[4];
    int idxs[KK] = {m0.x,m0.y,m0.z,m0.w, m1.x,m1.y,m1.z,m1.w, m2.x,m2.y,m2.z,m2.w,
                    m3.x,m3.y,m3.z,m3.w, m4.x,m4.y,m4.z,m4.w};

    // jax.image.resize linear: half-pixel centers + edge-normalized == clamped bilinear
    const float sc = 102.0f / 512.0f;        // exact in fp32
    float iny = ((float)y + 0.5f) * sc - 0.5f;
    float inx = ((float)x + 0.5f) * sc - 0.5f;
    float y0f = floorf(iny), x0f = floorf(inx);
    float fy = iny - y0f, fx = inx - x0f;
    int y0 = min(max((int)y0f, 0), HC - 1);
    int y1 = min(max((int)y0f + 1, 0), HC - 1);
    int x0 = min(max((int)x0f, 0), HC - 1);
    int x1 = min(max((int)x0f + 1, 0), HC - 1);
    const float4* q00 = (const float4*)(wk + (y0 * HC + x0) * KK);
    const float4* q01 = (const float4*)(wk + (y0 * HC + x1) * KK);
    const float4* q10 = (const float4*)(wk + (y1 * HC + x0) * KK);
    const float4* q11 = (const float4*)(wk + (y1 * HC + x1) * KK);

    // preblend widths (r16/r17-proven) -> LDS row
    #pragma unroll
    for (int r = 0; r < 5; ++r) {
        float4 a = q00[r], b = q01[r], c = q10[r], d = q11[r];
        wvl[tt0][4*r+0] = (1.0f - fy) * ((1.0f - fx) * a.x + fx * b.x)
                        +          fy * ((1.0f - fx) * c.x + fx * d.x);
        wvl[tt0][4*r+1] = (1.0f - fy) * ((1.0f - fx) * a.y + fx * b.y)
                        +          fy * ((1.0f - fx) * c.y + fx * d.y);
        wvl[tt0][4*r+2] = (1.0f - fy) * ((1.0f - fx) * a.z + fx * b.z)
                        +          fy * ((1.0f - fx) * c.z + fx * d.z);
        wvl[tt0][4*r+3] = (1.0f - fy) * ((1.0f - fx) * a.w + fx * b.w)
                        +          fy * ((1.0f - fx) * c.w + fx * d.w);
    }

    // chain A (even strokes) and chain B (odd strokes): independent dep chains
    float mA = -INFINITY, sA = 0.0f, a0A = 0.0f, a1A = 0.0f, a2A = 0.0f, waA = 0.0f;
    float mB = -INFINITY, sB = 0.0f, a0B = 0.0f, a1B = 0.0f, a2B = 0.0f, waB = 0.0f;
    float DA = INFINITY, DB = INFINITY;

    #pragma unroll 2
    for (int k = 0; k < KK; k += 2) {
        {   // ---- stroke k -> chain A (body frozen) ----
            const float4* sp = (const float4*)(sdata + idxs[k] * 32);
            float4 f0 = sp[0], f1 = sp[1], f2 = sp[2], f3 = sp[3], f4 = sp[4];
            float4 i0 = sp[5], i1 = sp[6], i2 = sp[7];
            float4 cw = ctab[idxs[k]];
            float qx[10] = {f0.x, f0.z, f1.x, f1.z, f2.x, f2.z, f3.x, f3.z, f4.x, f4.z};
            float qy[10] = {f0.y, f0.w, f1.y, f1.w, f2.y, f2.w, f3.y, f3.w, f4.y, f4.w};
            float iv[9]  = {i0.x, i0.y, i0.z, i0.w, i1.x, i1.y, i1.z, i1.w, i2.x};
            float mink = INFINITY;
            #pragma unroll
            for (int sg = 0; sg < 9; ++sg) {
                float ax = qx[sg], ay = qy[sg];
                float bx = qx[sg+1] - ax, by = qy[sg+1] - ay;
                float pax = p0 - ax, pay = p1 - ay;
                float dot = bx * pax + by * pay;
                float tt = dot * iv[sg];
                tt = fminf(fmaxf(tt, 0.0f), 1.0f);
                float ccx = ax + tt * bx, ccy = ay + tt * by;
                float ddx = p0 - ccx, ddy = p1 - ccy;
                float d = ddx * ddx + ddy * ddy;
                mink = fminf(mink, d);
            }
            DA = fminf(DA, mink);
            float z = 100000.0f / (1e-8f + mink);  // IEEE div: rounding-sensitive
            float nm  = fmaxf(mA, z);
            float scl = __expf(mA - nm);           // m=-inf first iter -> 0
            float e   = __expf(z - nm);
            sA  = sA  * scl + e;
            a0A = a0A * scl + cw.x * e;
            a1A = a1A * scl + cw.y * e;
            a2A = a2A * scl + cw.z * e;
            waA = waA * scl + wvl[tt0][k] * e;
            mA = nm;
        }
        {   // ---- stroke k+1 -> chain B (body frozen) ----
            const float4* sp = (const float4*)(sdata + idxs[k+1] * 32);
            float4 f0 = sp[0], f1 = sp[1], f2 = sp[2], f3 = sp[3], f4 = sp[4];
            float4 i0 = sp[5], i1 = sp[6], i2 = sp[7];
            float4 cw = ctab[idxs[k+1]];
            float qx[10] = {f0.x, f0.z, f1.x, f1.z, f2.x, f2.z, f3.x, f3.z, f4.x, f4.z};
            float qy[10] = {f0.y, f0.w, f1.y, f1.w, f2.y, f2.w, f3.y, f3.w, f4.y, f4.w};
            float iv[9]  = {i0.x, i0.y, i0.z, i0.w, i1.x, i1.y, i1.z, i1.w, i2.x};
            float mink = INFINITY;
            #pragma unroll
            for (int sg = 0; sg < 9; ++sg) {
                float ax = qx[sg], ay = qy[sg];
                float bx = qx[sg+1] - ax, by = qy[sg+1] - ay;
                float pax = p0 - ax, pay = p1 - ay;
                float dot = bx * pax + by * pay;
                float tt = dot * iv[sg];
                tt = fminf(fmaxf(tt, 0.0f), 1.0f);
                float ccx = ax + tt * bx, ccy = ay + tt * by;
                float ddx = p0 - ccx, ddy = p1 - ccy;
                float d = ddx * ddx + ddy * ddy;
                mink = fminf(mink, d);
            }
            DB = fminf(DB, mink);
            float z = 100000.0f / (1e-8f + mink);  // IEEE div: rounding-sensitive
            float nm  = fmaxf(mB, z);
            float scl = __expf(mB - nm);
            float e   = __expf(z - nm);
            sB  = sB  * scl + e;
            a0B = a0B * scl + cw.x * e;
            a1B = a1B * scl + cw.y * e;
            a2B = a2B * scl + cw.z * e;
            waB = waB * scl + wvl[tt0][k+1] * e;
            mB = nm;
        }
    }

    // merge chains (r13/14/15-proven rescale) + epilogue
    float nm = fmaxf(mA, mB);
    float eA = __expf(mA - nm), eB = __expf(mB - nm);
    float s  = sA  * eA + sB  * eB;
    float a0 = a0A * eA + a0B * eB;
    float a1 = a1A * eA + a1B * eB;
    float a2 = a2A * eA + a2B * eB;
    float wa = waA * eA + waB * eB;
    float D  = fminf(DA, DB);

    float inv = 1.0f / s;
    float bs = wa * inv;
    float msk = 1.0f / (1.0f + __expf(-(bs - D)));   // sigmoid
    float o0 = a0 * inv * msk + (1.0f - msk) * 0.5f;
    float o1 = a1 * inv * msk + (1.0f - msk) * 0.5f;
    float o2 = a2 * inv * msk + (1.0f - msk) * 0.5f;
    int base = (y * 512 + x) * 3;
    out[base+0] = o0;
    out[base+1] = o1;
    out[base+2] = o2;
}

extern "C" void kernel_launch(void* const* d_in, const int* in_sizes, int n_in,
                              void* d_out, int out_size, void* d_ws, size_t ws_size,
                              hipStream_t stream) {
    const float* cs    = (const float*)d_in[0];  // curve_s (5000,2)
    const float* ce    = (const float*)d_in[1];  // curve_e (5000,2)
    const float* cc    = (const float*)d_in[2];  // curve_c (5000,2)
    const float* color = (const float*)d_in[3];  // color   (5000,3)
    const float* loc   = (const float*)d_in[4];  // location(5000,2)
    const float* width = (const float*)d_in[5];  // width   (5000,1)
    float* out = (float*)d_out;

    char* p = (char*)d_ws;
    float*  sdata    = (float*)p;                 p += NS * 32 * sizeof(float);       // 640000
    float4* ctab     = (float4*)p;                p += NS * sizeof(float4);           // 80000
    int*    idcs     = (int*)p;                   p += (size_t)HC*HC*KK*sizeof(int);  // 832320
    float*  wk       = (float*)p;                 p += (size_t)HC*HC*KK*sizeof(float);// 832320
    int*    binCntP  = (int*)p;                   p += NPB * NBIN*NBIN * sizeof(int); // 81920
    int*    binStart = (int*)p;                   p += 4112;                          // 1025 ints + pad
    float2* sxy      = (float2*)p;                p += NS * sizeof(float2);           // 40000
    int*    sid      = (int*)p;                   /* 20000 */

    prep_kernel   <<<NPB, 256, 0, stream>>>(cs, ce, cc, loc, color, width, sdata, ctab, binCntP);
    scatter_kernel<<<NPB, 256, 0, stream>>>(loc, binCntP, binStart, sxy, sid);
    topk_kernel   <<<(HC*HC)/4, 256, 0, stream>>>(loc, width, sxy, sid, binStart, idcs, wk);
    render_kernel <<<dim3(32, 32), 256, 0, stream>>>(sdata, ctab, idcs, wk, out);
}

// Round 19
// 128.299 us; speedup vs baseline: 1.2432x; 1.0003x over previous
//
#include <hip/hip_runtime.h>
#include <math.h>

#define NS 5000
#define SS 10
#define KK 20
#define HC 102
#define NBIN 32
#define BINW 16.0f
#define NPB 20           // prep/scatter blocks: ceil(5000/256)
#define CAP 192          // per-wave candidate capacity (P(overflow) ~ 0)

// Wave-level LDS sync: drain LDS ops + compiler ordering. Waves own private
// LDS slices; no block barrier needed (escalation may diverge between waves).
#define WAVE_SYNC() __asm__ volatile("s_waitcnt lgkmcnt(0)" ::: "memory")

// ---------- Kernel 1: stroke records + per-block bin counts (r12 verbatim) ----------
__global__ void __launch_bounds__(256) prep_kernel(
        const float* __restrict__ cs, const float* __restrict__ ce,
        const float* __restrict__ cc, const float* __restrict__ loc,
        const float* __restrict__ color, const float* __restrict__ width,
        float* __restrict__ sdata, float4* __restrict__ ctab,
        int* __restrict__ binCntP) {
    __shared__ int4 lcnt4[NBIN*NBIN/4];          // int4 decl guarantees 16B alignment
    int* lcnt = (int*)lcnt4;
    int t = threadIdx.x;
    lcnt4[t] = make_int4(0, 0, 0, 0);
    __syncthreads();
    int i = blockIdx.x * 256 + t;
    if (i < NS) {
        float lx = loc[i*2+0], ly = loc[i*2+1];
        float sx = cs[i*2+0] + lx, sy = cs[i*2+1] + ly;
        float ex = ce[i*2+0] + lx, ey = ce[i*2+1] + ly;
        float px = cc[i*2+0] + lx, py = cc[i*2+1] + ly;
        float qx[SS], qy[SS];
        #pragma unroll
        for (int j = 0; j < SS; ++j) {
            float tt = (float)j * (1.0f / 9.0f);   // linspace(0,1,10) step in fp32
            float omt = 1.0f - tt;
            float omt2 = omt * omt, t2 = tt * tt;
            qx[j] = px + omt2 * (sx - px) + t2 * (ex - px);
            qy[j] = py + omt2 * (sy - py) + t2 * (ey - py);
            sdata[i*32 + 2*j + 0] = qx[j];
            sdata[i*32 + 2*j + 1] = qy[j];
        }
        #pragma unroll
        for (int sg = 0; sg < 9; ++sg) {
            float bx = qx[sg+1] - qx[sg], by = qy[sg+1] - qy[sg];
            sdata[i*32 + 20 + sg] = 1.0f / (bx*bx + by*by);   // full precision
        }
        sdata[i*32 + 29] = 0.0f; sdata[i*32 + 30] = 0.0f; sdata[i*32 + 31] = 0.0f;
        ctab[i] = make_float4(color[i*3+0], color[i*3+1], color[i*3+2], width[i]);
        int b0 = min(max((int)(lx * (1.0f/BINW)), 0), NBIN-1);
        int b1 = min(max((int)(ly * (1.0f/BINW)), 0), NBIN-1);
        atomicAdd(&lcnt[b0*NBIN + b1], 1);
    }
    __syncthreads();
    ((int4*)binCntP)[blockIdx.x * 256 + t] = lcnt4[t];
}

// ---------- Kernel 2: redundant per-block scan + CSR scatter (r12 verbatim) ----------
__global__ void __launch_bounds__(256) scatter_kernel(
        const float* __restrict__ loc, const int* __restrict__ binCntP,
        int* __restrict__ binStart, float2* __restrict__ sxy, int* __restrict__ sid) {
    __shared__ int fill[NBIN*NBIN];
    __shared__ int wsum[4];
    int t = threadIdx.x, lane = t & 63, w = t >> 6;
    int mb = blockIdx.x;
    int4 tot = make_int4(0,0,0,0), bel = make_int4(0,0,0,0);
    for (int b = 0; b < NPB; ++b) {
        int4 v = ((const int4*)binCntP)[b * 256 + t];
        tot.x += v.x; tot.y += v.y; tot.z += v.z; tot.w += v.w;
        if (b < mb) { bel.x += v.x; bel.y += v.y; bel.z += v.z; bel.w += v.w; }
    }
    int s0 = tot.x, s1 = s0 + tot.y, s2 = s1 + tot.z, s3 = s2 + tot.w;
    int x = s3;
    #pragma unroll
    for (int off = 1; off < 64; off <<= 1) {
        int y = __shfl_up(x, off, 64);
        if (lane >= off) x += y;
    }
    if (lane == 63) wsum[w] = x;
    __syncthreads();
    int woff = 0;
    #pragma unroll
    for (int i = 0; i < 4; ++i) woff += (i < w) ? wsum[i] : 0;
    int texcl = woff + x - s3;           // exclusive prefix of this thread's 4 bins
    fill[4*t+0] = texcl      + bel.x;
    fill[4*t+1] = texcl + s0 + bel.y;
    fill[4*t+2] = texcl + s1 + bel.z;
    fill[4*t+3] = texcl + s2 + bel.w;
    if (mb == 0) {                       // publish global scan for topk
        binStart[4*t+1] = texcl + s0;
        binStart[4*t+2] = texcl + s1;
        binStart[4*t+3] = texcl + s2;
        binStart[4*t+4] = texcl + s3;
        if (t == 0) binStart[0] = 0;
    }
    __syncthreads();
    int i = mb * 256 + t;
    if (i < NS) {
        float l0 = loc[i*2+0], l1 = loc[i*2+1];
        int b0 = min(max((int)(l0 * (1.0f/BINW)), 0), NBIN-1);
        int b1 = min(max((int)(l1 * (1.0f/BINW)), 0), NBIN-1);
        int pos = atomicAdd(&fill[b0*NBIN + b1], 1);
        sxy[pos] = make_float2(l0, l1);
        sid[pos] = i;
    }
}

// ---------- Kernel 3: per-cell top-20, latency-batched row gathers ----------
// The old serial bin-row loop exposed one dependent ~300-400 cyc gather per
// row (4-5 rows). New: when nrows<=6 (always at R=26), read all row bounds,
// issue ALL rows' sxy/sid gathers back-to-back into registers (ILP -> one
// latency exposure), then ballot-compact from registers. Rare >64-stroke
// segments get an exact tail loop. Selection math unchanged; exactness is
// insertion-order-independent (unique keys, rank-scatter). Escalations with
// nrows>6 use the original serial path.
__global__ void __launch_bounds__(256) topk_kernel(const float* __restrict__ loc,
                                                   const float* __restrict__ width,
                                                   const float2* __restrict__ sxy,
                                                   const int* __restrict__ sid,
                                                   const int* __restrict__ binStart,
                                                   int* __restrict__ idcs,
                                                   float* __restrict__ wk) {
    __shared__ unsigned long long sk[4][CAP];
    int w = threadIdx.x >> 6, lane = threadIdx.x & 63;
    int cell = blockIdx.x * 4 + w;                 // grid covers exactly HC*HC
    int ci = cell / HC, cj = cell - ci * HC;
    const float dc = 512.0f / 101.0f;              // linspace(0,512,102) step in fp32
    float c0 = (float)ci * dc;
    float c1 = (float)cj * dc;
    unsigned long long below = (1ull << lane) - 1ull;

    float R = 26.0f;                               // E[cnt] ~ 40; P(cnt<20) ~ 2e-4
    int cnt = 0;
    for (int attempt = 0; attempt < 5; ++attempt) {
        float R2 = R * R;
        int base = 0;
        int by0 = max((int)((c0 - R) * (1.0f/BINW)), 0);
        int by1 = min((int)((c0 + R) * (1.0f/BINW)), NBIN-1);
        int bx0 = max((int)((c1 - R) * (1.0f/BINW)), 0);
        int bx1 = min((int)((c1 + R) * (1.0f/BINW)), NBIN-1);
        int nrows = by1 - by0 + 1;
        if (nrows <= 6) {
            // ---- batched path ----
            int rs[6], re[6];
            #pragma unroll
            for (int r = 0; r < 6; ++r) {
                bool va = (r < nrows);
                int by = va ? (by0 + r) : by0;
                rs[r] = binStart[by*NBIN + bx0];
                re[r] = va ? binStart[by*NBIN + bx1 + 1] : rs[r];  // empty if !va
            }
            float2 pr[6]; int idr[6];
            #pragma unroll
            for (int r = 0; r < 6; ++r) {          // all gathers in flight together
                int t  = rs[r] + lane;
                int tc = max(min(t, re[r] - 1), 0);
                pr[r]  = sxy[tc];
                idr[r] = sid[tc];
            }
            #pragma unroll
            for (int r = 0; r < 6; ++r) {
                int t = rs[r] + lane;
                float dx = c0 - pr[r].x, dy = c1 - pr[r].y;
                float d = dx*dx + dy*dy;
                bool pred = (t < re[r]) && (d < R2);
                unsigned long long mask = __ballot(pred);
                int pos = base + __popcll(mask & below);
                if (pred && pos < CAP)
                    sk[w][pos] = ((unsigned long long)__float_as_uint(d) << 32)
                               | (unsigned int)idr[r];
                base += __popcll(mask);
                // exactness tail for segments > 64 strokes (P ~ 1e-11)
                for (int t0 = rs[r] + 64; t0 < re[r]; t0 += 64) {
                    int t2  = t0 + lane;
                    int tc2 = min(t2, re[r] - 1);
                    float2 p = sxy[tc2];
                    float ex = c0 - p.x, ey = c1 - p.y;
                    float d2 = ex*ex + ey*ey;
                    bool p2 = (t2 < re[r]) && (d2 < R2);
                    unsigned long long m2 = __ballot(p2);
                    int pos2 = base + __popcll(m2 & below);
                    if (p2 && pos2 < CAP)
                        sk[w][pos2] = ((unsigned long long)__float_as_uint(d2) << 32)
                                    | (unsigned int)sid[tc2];
                    base += __popcll(m2);
                }
            }
        } else {
            // ---- original serial path (escalated windows) ----
            for (int by = by0; by <= by1; ++by) {
                int s = binStart[by*NBIN + bx0];
                int e = binStart[by*NBIN + bx1 + 1];
                for (int t0 = s; t0 < e; t0 += 64) {
                    int t = t0 + lane;
                    int tc = min(t, e - 1);
                    float2 p = sxy[tc];
                    float dx = c0 - p.x, dy = c1 - p.y;
                    float d = dx*dx + dy*dy;
                    bool pred = (t < e) && (d < R2);
                    unsigned long long mask = __ballot(pred);
                    int pos = base + __popcll(mask & below);
                    if (pred && pos < CAP)
                        sk[w][pos] = ((unsigned long long)__float_as_uint(d) << 32)
                                   | (unsigned int)sid[tc];
                    base += __popcll(mask);
                }
            }
        }
        cnt = base;
        if (cnt >= KK) break;                      // includes overflow -> fallback below
        R *= 1.6f;
    }
    WAVE_SYNC();

    if (cnt >= KK && cnt <= CAP) {
        if (cnt <= 64) {
            unsigned long long k0 = (lane < cnt) ? sk[w][lane] : ~0ull;
            int r0 = 0;
            int j = 0;
            #pragma unroll 1
            for (; j + 4 <= cnt; j += 4) {
                unsigned long long a = sk[w][j],   b = sk[w][j+1];
                unsigned long long c = sk[w][j+2], d = sk[w][j+3];
                r0 += (int)(a < k0) + (int)(b < k0) + (int)(c < k0) + (int)(d < k0);
            }
            for (; j < cnt; ++j) r0 += (int)(sk[w][j] < k0);
            if (r0 < KK && lane < cnt) {
                int idx = (int)(unsigned int)(k0 & 0xffffffffull);
                idcs[cell*KK + r0] = idx;
                wk[cell*KK + r0]   = width[idx];
            }
        } else {
            unsigned long long k0 = (lane       < cnt) ? sk[w][lane]       : ~0ull;
            unsigned long long k1 = (lane + 64  < cnt) ? sk[w][lane + 64]  : ~0ull;
            unsigned long long k2 = (lane + 128 < cnt) ? sk[w][lane + 128] : ~0ull;
            int r0 = 0, r1 = 0, r2 = 0;
            #pragma unroll 1
            for (int j = 0; j < cnt; ++j) {
                unsigned long long a = sk[w][j];
                r0 += (int)(a < k0); r1 += (int)(a < k1); r2 += (int)(a < k2);
            }
            if (r0 < KK && lane < cnt) {
                int idx = (int)(unsigned int)(k0 & 0xffffffffull);
                idcs[cell*KK + r0] = idx;  wk[cell*KK + r0] = width[idx];
            }
            if (r1 < KK && lane + 64 < cnt) {
                int idx = (int)(unsigned int)(k1 & 0xffffffffull);
                idcs[cell*KK + r1] = idx;  wk[cell*KK + r1] = width[idx];
            }
            if (r2 < KK && lane + 128 < cnt) {
                int idx = (int)(unsigned int)(k2 & 0xffffffffull);
                idcs[cell*KK + r2] = idx;  wk[cell*KK + r2] = width[idx];
            }
        }
    } else {
        if (lane == 0) {                 // exactness fallback (statistically never)
            float bd[KK]; int bi[KK];
            for (int k = 0; k < KK; ++k) { bd[k] = 3.4e38f; bi[k] = 0; }
            for (int n = 0; n < NS; ++n) {
                float dx = c0 - loc[n*2+0];
                float dy = c1 - loc[n*2+1];
                float d = dx*dx + dy*dy;
                if (d < bd[KK-1]) {
                    int p = KK - 1;
                    while (p > 0 && bd[p-1] > d) { bd[p] = bd[p-1]; bi[p] = bi[p-1]; --p; }
                    bd[p] = d; bi[p] = n;
                }
            }
            for (int k = 0; k < KK; ++k) {
                idcs[cell*KK + k] = bi[k];
                wk[cell*KK + k]   = width[bi[k]];
            }
        }
    }
}

// ---------- Kernel 4: render (r17 verbatim — FROZEN) ----------
// 8 variants (r11..r18) pinned at 44+-1 us; occupancy/divergence/load-count/
// dep-chain all falsified. sg-loop + softmax numerics frozen (mink->z is
// ulp-sensitive at stroke intersections — r9/r10 failures).
__global__ void __launch_bounds__(256, 4) render_kernel(const float* __restrict__ sdata,
                                                        const float4* __restrict__ ctab,
                                                        const int* __restrict__ idcs,
                                                        const float* __restrict__ wk,
                                                        float* __restrict__ out) {
    __shared__ float wvl[256][21];           // 21.5 KB; stride 21 breaks bank aliasing
    int tt0 = threadIdx.x, lane = tt0 & 63, wq = tt0 >> 6;
    int x = blockIdx.x * 16 + ((wq & 1) << 3) + (lane & 7);   // wave = 8x8 pixel tile
    int y = blockIdx.y * 16 + ((wq >> 1) << 3) + (lane >> 3);
    const float df = 512.0f / 511.0f;        // linspace(0,512,512) step in fp32
    float p0 = (float)y * df;                // H-coordinate
    float p1 = (float)x * df;                // W-coordinate
    int cy = (y * 51) >> 8;                  // floor(y*102/512), exact vs fp32 ref
    int cx = (x * 51) >> 8;

    // preload all 20 stroke indices (aligned: cell*20 ints = 80 B)
    const int4* mip = (const int4*)(idcs + (cy * HC + cx) * KK);
    int4 m0 = mip[0], m1 = mip[1], m2 = mip[2], m3 = mip[3], m4 = mip[4];
    int idxs[KK] = {m0.x,m0.y,m0.z,m0.w, m1.x,m1.y,m1.z,m1.w, m2.x,m2.y,m2.z,m2.w,
                    m3.x,m3.y,m3.z,m3.w, m4.x,m4.y,m4.z,m4.w};

    // jax.image.resize linear: half-pixel centers + edge-normalized == clamped bilinear
    const float sc = 102.0f / 512.0f;        // exact in fp32
    float iny = ((float)y + 0.5f) * sc - 0.5f;
    float inx = ((float)x + 0.5f) * sc - 0.5f;
    float y0f = floorf(iny), x0f = floorf(inx);
    float fy = iny - y0f, fx = inx - x0f;
    int y0 = min(max((int)y0f, 0), HC - 1);
    int y1 = min(max((int)y0f + 1, 0), HC - 1);
    int x0 = min(max((int)x0f, 0), HC - 1);
    int x1 = min(max((int)x0f + 1, 0), HC - 1);
    const float4* q00 = (const float4*)(wk + (y0 * HC + x0) * KK);
    const float4* q01 = (const float4*)(wk + (y0 * HC + x1) * KK);
    const float4* q10 = (const float4*)(wk + (y1 * HC + x0) * KK);
    const float4* q11 = (const float4*)(wk + (y1 * HC + x1) * KK);

    // preblend widths (r16/r17-proven) -> LDS row
    #pragma unroll
    for (int r = 0; r < 5; ++r) {
        float4 a = q00[r], b = q01[r], c = q10[r], d = q11[r];
        wvl[tt0][4*r+0] = (1.0f - fy) * ((1.0f - fx) * a.x + fx * b.x)
                        +          fy * ((1.0f - fx) * c.x + fx * d.x);
        wvl[tt0][4*r+1] = (1.0f - fy) * ((1.0f - fx) * a.y + fx * b.y)
                        +          fy * ((1.0f - fx) * c.y + fx * d.y);
        wvl[tt0][4*r+2] = (1.0f - fy) * ((1.0f - fx) * a.z + fx * b.z)
                        +          fy * ((1.0f - fx) * c.z + fx * d.z);
        wvl[tt0][4*r+3] = (1.0f - fy) * ((1.0f - fx) * a.w + fx * b.w)
                        +          fy * ((1.0f - fx) * c.w + fx * d.w);
    }

    float m = -INFINITY, s = 0.0f;
    float a0 = 0.0f, a1 = 0.0f, a2 = 0.0f, wa = 0.0f;
    float D = INFINITY;

    #pragma unroll 4
    for (int k = 0; k < KK; ++k) {
        const float4* sp = (const float4*)(sdata + idxs[k] * 32);
        float4 f0 = sp[0], f1 = sp[1], f2 = sp[2], f3 = sp[3], f4 = sp[4];
        float4 i0 = sp[5], i1 = sp[6], i2 = sp[7];
        float4 cw = ctab[idxs[k]];
        float qx[10] = {f0.x, f0.z, f1.x, f1.z, f2.x, f2.z, f3.x, f3.z, f4.x, f4.z};
        float qy[10] = {f0.y, f0.w, f1.y, f1.w, f2.y, f2.w, f3.y, f3.w, f4.y, f4.w};
        float iv[9]  = {i0.x, i0.y, i0.z, i0.w, i1.x, i1.y, i1.z, i1.w, i2.x};
        float mink = INFINITY;
        #pragma unroll
        for (int sg = 0; sg < 9; ++sg) {
            float ax = qx[sg], ay = qy[sg];
            float bx = qx[sg+1] - ax, by = qy[sg+1] - ay;
            float pax = p0 - ax, pay = p1 - ay;
            float dot = bx * pax + by * pay;
            float tt = dot * iv[sg];
            tt = fminf(fmaxf(tt, 0.0f), 1.0f);
            float ccx = ax + tt * bx, ccy = ay + tt * by;
            float ddx = p0 - ccx, ddy = p1 - ccy;
            float d = ddx * ddx + ddy * ddy;
            mink = fminf(mink, d);
        }
        D = fminf(D, mink);
        float z = 100000.0f / (1e-8f + mink);    // IEEE div: exponent is rounding-sensitive
        // branchless online softmax (== subtract-max softmax, exp(0)==1 exactly)
        float nm  = fmaxf(m, z);
        float scl = __expf(m - nm);              // m=-inf first iter -> 0
        float e   = __expf(z - nm);
        s  = s  * scl + e;
        a0 = a0 * scl + cw.x * e;
        a1 = a1 * scl + cw.y * e;
        a2 = a2 * scl + cw.z * e;
        wa = wa * scl + wvl[tt0][k] * e;
        m = nm;
    }
    float inv = 1.0f / s;
    float bs = wa * inv;
    float msk = 1.0f / (1.0f + __expf(-(bs - D)));   // sigmoid
    float o0 = a0 * inv * msk + (1.0f - msk) * 0.5f;
    float o1 = a1 * inv * msk + (1.0f - msk) * 0.5f;
    float o2 = a2 * inv * msk + (1.0f - msk) * 0.5f;
    int base = (y * 512 + x) * 3;
    out[base+0] = o0;
    out[base+1] = o1;
    out[base+2] = o2;
}

extern "C" void kernel_launch(void* const* d_in, const int* in_sizes, int n_in,
                              void* d_out, int out_size, void* d_ws, size_t ws_size,
                              hipStream_t stream) {
    const float* cs    = (const float*)d_in[0];  // curve_s (5000,2)
    const float* ce    = (const float*)d_in[1];  // curve_e (5000,2)
    const float* cc    = (const float*)d_in[2];  // curve_c (5000,2)
    const float* color = (const float*)d_in[3];  // color   (5000,3)
    const float* loc   = (const float*)d_in[4];  // location(5000,2)
    const float* width = (const float*)d_in[5];  // width   (5000,1)
    float* out = (float*)d_out;

    char* p = (char*)d_ws;
    float*  sdata    = (float*)p;                 p += NS * 32 * sizeof(float);       // 640000
    float4* ctab     = (float4*)p;                p += NS * sizeof(float4);           // 80000
    int*    idcs     = (int*)p;                   p += (size_t)HC*HC*KK*sizeof(int);  // 832320
    float*  wk       = (float*)p;                 p += (size_t)HC*HC*KK*sizeof(float);// 832320
    int*    binCntP  = (int*)p;                   p += NPB * NBIN*NBIN * sizeof(int); // 81920
    int*    binStart = (int*)p;                   p += 4112;                          // 1025 ints + pad
    float2* sxy      = (float2*)p;                p += NS * sizeof(float2);           // 40000
    int*    sid      = (int*)p;                   /* 20000 */

    prep_kernel   <<<NPB, 256, 0, stream>>>(cs, ce, cc, loc, color, width, sdata, ctab, binCntP);
    scatter_kernel<<<NPB, 256, 0, stream>>>(loc, binCntP, binStart, sxy, sid);
    topk_kernel   <<<(HC*HC)/4, 256, 0, stream>>>(loc, width, sxy, sid, binStart, idcs, wk);
    render_kernel <<<dim3(32, 32), 256, 0, stream>>>(sdata, ctab, idcs, wk, out);
}

// Round 20
// 116.866 us; speedup vs baseline: 1.3648x; 1.0978x over previous
//
#include <hip/hip_runtime.h>
#include <math.h>

#define NS 5000
#define SS 10
#define KK 20
#define HC 102
#define NBIN 32
#define BINW 16.0f
#define NPB 20           // prep/scatter blocks: ceil(5000/256)
#define CAP 192          // per-wave candidate capacity (P(overflow) ~ 0)

// Wave-level LDS sync: drain LDS ops + compiler ordering. Waves own private
// LDS slices; no block barrier needed (escalation may diverge between waves).
#define WAVE_SYNC() __asm__ volatile("s_waitcnt lgkmcnt(0)" ::: "memory")

// ---------- Kernel 1: stroke records + per-block bin counts (r12 verbatim) ----------
__global__ void __launch_bounds__(256) prep_kernel(
        const float* __restrict__ cs, const float* __restrict__ ce,
        const float* __restrict__ cc, const float* __restrict__ loc,
        const float* __restrict__ color, const float* __restrict__ width,
        float* __restrict__ sdata, float4* __restrict__ ctab,
        int* __restrict__ binCntP) {
    __shared__ int4 lcnt4[NBIN*NBIN/4];          // int4 decl guarantees 16B alignment
    int* lcnt = (int*)lcnt4;
    int t = threadIdx.x;
    lcnt4[t] = make_int4(0, 0, 0, 0);
    __syncthreads();
    int i = blockIdx.x * 256 + t;
    if (i < NS) {
        float lx = loc[i*2+0], ly = loc[i*2+1];
        float sx = cs[i*2+0] + lx, sy = cs[i*2+1] + ly;
        float ex = ce[i*2+0] + lx, ey = ce[i*2+1] + ly;
        float px = cc[i*2+0] + lx, py = cc[i*2+1] + ly;
        float qx[SS], qy[SS];
        #pragma unroll
        for (int j = 0; j < SS; ++j) {
            float tt = (float)j * (1.0f / 9.0f);   // linspace(0,1,10) step in fp32
            float omt = 1.0f - tt;
            float omt2 = omt * omt, t2 = tt * tt;
            qx[j] = px + omt2 * (sx - px) + t2 * (ex - px);
            qy[j] = py + omt2 * (sy - py) + t2 * (ey - py);
            sdata[i*32 + 2*j + 0] = qx[j];
            sdata[i*32 + 2*j + 1] = qy[j];
        }
        #pragma unroll
        for (int sg = 0; sg < 9; ++sg) {
            float bx = qx[sg+1] - qx[sg], by = qy[sg+1] - qy[sg];
            sdata[i*32 + 20 + sg] = 1.0f / (bx*bx + by*by);   // full precision
        }
        sdata[i*32 + 29] = 0.0f; sdata[i*32 + 30] = 0.0f; sdata[i*32 + 31] = 0.0f;
        ctab[i] = make_float4(color[i*3+0], color[i*3+1], color[i*3+2], width[i]);
        int b0 = min(max((int)(lx * (1.0f/BINW)), 0), NBIN-1);
        int b1 = min(max((int)(ly * (1.0f/BINW)), 0), NBIN-1);
        atomicAdd(&lcnt[b0*NBIN + b1], 1);
    }
    __syncthreads();
    ((int4*)binCntP)[blockIdx.x * 256 + t] = lcnt4[t];
}

// ---------- Kernel 2: redundant per-block scan + CSR scatter (r12 verbatim) ----------
__global__ void __launch_bounds__(256) scatter_kernel(
        const float* __restrict__ loc, const int* __restrict__ binCntP,
        int* __restrict__ binStart, float2* __restrict__ sxy, int* __restrict__ sid) {
    __shared__ int fill[NBIN*NBIN];
    __shared__ int wsum[4];
    int t = threadIdx.x, lane = t & 63, w = t >> 6;
    int mb = blockIdx.x;
    int4 tot = make_int4(0,0,0,0), bel = make_int4(0,0,0,0);
    for (int b = 0; b < NPB; ++b) {
        int4 v = ((const int4*)binCntP)[b * 256 + t];
        tot.x += v.x; tot.y += v.y; tot.z += v.z; tot.w += v.w;
        if (b < mb) { bel.x += v.x; bel.y += v.y; bel.z += v.z; bel.w += v.w; }
    }
    int s0 = tot.x, s1 = s0 + tot.y, s2 = s1 + tot.z, s3 = s2 + tot.w;
    int x = s3;
    #pragma unroll
    for (int off = 1; off < 64; off <<= 1) {
        int y = __shfl_up(x, off, 64);
        if (lane >= off) x += y;
    }
    if (lane == 63) wsum[w] = x;
    __syncthreads();
    int woff = 0;
    #pragma unroll
    for (int i = 0; i < 4; ++i) woff += (i < w) ? wsum[i] : 0;
    int texcl = woff + x - s3;           // exclusive prefix of this thread's 4 bins
    fill[4*t+0] = texcl      + bel.x;
    fill[4*t+1] = texcl + s0 + bel.y;
    fill[4*t+2] = texcl + s1 + bel.z;
    fill[4*t+3] = texcl + s2 + bel.w;
    if (mb == 0) {                       // publish global scan for topk
        binStart[4*t+1] = texcl + s0;
        binStart[4*t+2] = texcl + s1;
        binStart[4*t+3] = texcl + s2;
        binStart[4*t+4] = texcl + s3;
        if (t == 0) binStart[0] = 0;
    }
    __syncthreads();
    int i = mb * 256 + t;
    if (i < NS) {
        float l0 = loc[i*2+0], l1 = loc[i*2+1];
        int b0 = min(max((int)(l0 * (1.0f/BINW)), 0), NBIN-1);
        int b1 = min(max((int)(l1 * (1.0f/BINW)), 0), NBIN-1);
        int pos = atomicAdd(&fill[b0*NBIN + b1], 1);
        sxy[pos] = make_float2(l0, l1);
        sid[pos] = i;
    }
}

// ---------- Kernel 3: per-cell top-20 (r19 verbatim: exact, batched gathers) ----------
__global__ void __launch_bounds__(256) topk_kernel(const float* __restrict__ loc,
                                                   const float* __restrict__ width,
                                                   const float2* __restrict__ sxy,
                                                   const int* __restrict__ sid,
                                                   const int* __restrict__ binStart,
                                                   int* __restrict__ idcs,
                                                   float* __restrict__ wk) {
    __shared__ unsigned long long sk[4][CAP];
    int w = threadIdx.x >> 6, lane = threadIdx.x & 63;
    int cell = blockIdx.x * 4 + w;                 // grid covers exactly HC*HC
    int ci = cell / HC, cj = cell - ci * HC;
    const float dc = 512.0f / 101.0f;              // linspace(0,512,102) step in fp32
    float c0 = (float)ci * dc;
    float c1 = (float)cj * dc;
    unsigned long long below = (1ull << lane) - 1ull;

    float R = 26.0f;                               // E[cnt] ~ 40; P(cnt<20) ~ 2e-4
    int cnt = 0;
    for (int attempt = 0; attempt < 5; ++attempt) {
        float R2 = R * R;
        int base = 0;
        int by0 = max((int)((c0 - R) * (1.0f/BINW)), 0);
        int by1 = min((int)((c0 + R) * (1.0f/BINW)), NBIN-1);
        int bx0 = max((int)((c1 - R) * (1.0f/BINW)), 0);
        int bx1 = min((int)((c1 + R) * (1.0f/BINW)), NBIN-1);
        int nrows = by1 - by0 + 1;
        if (nrows <= 6) {
            int rs[6], re[6];
            #pragma unroll
            for (int r = 0; r < 6; ++r) {
                bool va = (r < nrows);
                int by = va ? (by0 + r) : by0;
                rs[r] = binStart[by*NBIN + bx0];
                re[r] = va ? binStart[by*NBIN + bx1 + 1] : rs[r];
            }
            float2 pr[6]; int idr[6];
            #pragma unroll
            for (int r = 0; r < 6; ++r) {          // all gathers in flight together
                int t  = rs[r] + lane;
                int tc = max(min(t, re[r] - 1), 0);
                pr[r]  = sxy[tc];
                idr[r] = sid[tc];
            }
            #pragma unroll
            for (int r = 0; r < 6; ++r) {
                int t = rs[r] + lane;
                float dx = c0 - pr[r].x, dy = c1 - pr[r].y;
                float d = dx*dx + dy*dy;
                bool pred = (t < re[r]) && (d < R2);
                unsigned long long mask = __ballot(pred);
                int pos = base + __popcll(mask & below);
                if (pred && pos < CAP)
                    sk[w][pos] = ((unsigned long long)__float_as_uint(d) << 32)
                               | (unsigned int)idr[r];
                base += __popcll(mask);
                for (int t0 = rs[r] + 64; t0 < re[r]; t0 += 64) {  // exact tail
                    int t2  = t0 + lane;
                    int tc2 = min(t2, re[r] - 1);
                    float2 p = sxy[tc2];
                    float ex = c0 - p.x, ey = c1 - p.y;
                    float d2 = ex*ex + ey*ey;
                    bool p2 = (t2 < re[r]) && (d2 < R2);
                    unsigned long long m2 = __ballot(p2);
                    int pos2 = base + __popcll(m2 & below);
                    if (p2 && pos2 < CAP)
                        sk[w][pos2] = ((unsigned long long)__float_as_uint(d2) << 32)
                                    | (unsigned int)sid[tc2];
                    base += __popcll(m2);
                }
            }
        } else {
            for (int by = by0; by <= by1; ++by) {  // escalated windows: serial path
                int s = binStart[by*NBIN + bx0];
                int e = binStart[by*NBIN + bx1 + 1];
                for (int t0 = s; t0 < e; t0 += 64) {
                    int t = t0 + lane;
                    int tc = min(t, e - 1);
                    float2 p = sxy[tc];
                    float dx = c0 - p.x, dy = c1 - p.y;
                    float d = dx*dx + dy*dy;
                    bool pred = (t < e) && (d < R2);
                    unsigned long long mask = __ballot(pred);
                    int pos = base + __popcll(mask & below);
                    if (pred && pos < CAP)
                        sk[w][pos] = ((unsigned long long)__float_as_uint(d) << 32)
                                   | (unsigned int)sid[tc];
                    base += __popcll(mask);
                }
            }
        }
        cnt = base;
        if (cnt >= KK) break;                      // includes overflow -> fallback below
        R *= 1.6f;
    }
    WAVE_SYNC();

    if (cnt >= KK && cnt <= CAP) {
        if (cnt <= 64) {
            unsigned long long k0 = (lane < cnt) ? sk[w][lane] : ~0ull;
            int r0 = 0;
            int j = 0;
            #pragma unroll 1
            for (; j + 4 <= cnt; j += 4) {
                unsigned long long a = sk[w][j],   b = sk[w][j+1];
                unsigned long long c = sk[w][j+2], d = sk[w][j+3];
                r0 += (int)(a < k0) + (int)(b < k0) + (int)(c < k0) + (int)(d < k0);
            }
            for (; j < cnt; ++j) r0 += (int)(sk[w][j] < k0);
            if (r0 < KK && lane < cnt) {
                int idx = (int)(unsigned int)(k0 & 0xffffffffull);
                idcs[cell*KK + r0] = idx;
                wk[cell*KK + r0]   = width[idx];
            }
        } else {
            unsigned long long k0 = (lane       < cnt) ? sk[w][lane]       : ~0ull;
            unsigned long long k1 = (lane + 64  < cnt) ? sk[w][lane + 64]  : ~0ull;
            unsigned long long k2 = (lane + 128 < cnt) ? sk[w][lane + 128] : ~0ull;
            int r0 = 0, r1 = 0, r2 = 0;
            #pragma unroll 1
            for (int j = 0; j < cnt; ++j) {
                unsigned long long a = sk[w][j];
                r0 += (int)(a < k0); r1 += (int)(a < k1); r2 += (int)(a < k2);
            }
            if (r0 < KK && lane < cnt) {
                int idx = (int)(unsigned int)(k0 & 0xffffffffull);
                idcs[cell*KK + r0] = idx;  wk[cell*KK + r0] = width[idx];
            }
            if (r1 < KK && lane + 64 < cnt) {
                int idx = (int)(unsigned int)(k1 & 0xffffffffull);
                idcs[cell*KK + r1] = idx;  wk[cell*KK + r1] = width[idx];
            }
            if (r2 < KK && lane + 128 < cnt) {
                int idx = (int)(unsigned int)(k2 & 0xffffffffull);
                idcs[cell*KK + r2] = idx;  wk[cell*KK + r2] = width[idx];
            }
        }
    } else {
        if (lane == 0) {                 // exactness fallback (statistically never)
            float bd[KK]; int bi[KK];
            for (int k = 0; k < KK; ++k) { bd[k] = 3.4e38f; bi[k] = 0; }
            for (int n = 0; n < NS; ++n) {
                float dx = c0 - loc[n*2+0];
                float dy = c1 - loc[n*2+1];
                float d = dx*dx + dy*dy;
                if (d < bd[KK-1]) {
                    int p = KK - 1;
                    while (p > 0 && bd[p-1] > d) { bd[p] = bd[p-1]; bi[p] = bi[p-1]; --p; }
                    bd[p] = d; bi[p] = n;
                }
            }
            for (int k = 0; k < KK; ++k) {
                idcs[cell*KK + k] = bi[k];
                wk[cell*KK + k]   = width[bi[k]];
            }
        }
    }
}

// ---------- Kernel 4: render — LDS-staged stroke records (final structural probe) ----------
// A 16x16 block maps into a 4x4 coarse-cell window (15*51>>8 < 3, and
// cy0+3 <= 101 for all blocks — no clamp needed). Stage the window's
// 16 cells x 20 records (32f sdata + ctab) into LDS cooperatively (each
// record = 8 coalesced float4), one barrier, then the FROZEN k-loop reads
// ds_read_b128 instead of divergent L2 loads. Bit-identical values; only
// the memory path changes. wk gathers return in-loop (r12 form, proven).
__global__ void __launch_bounds__(256, 4) render_kernel(const float* __restrict__ sdata,
                                                        const float4* __restrict__ ctab,
                                                        const int* __restrict__ idcs,
                                                        const float* __restrict__ wk,
                                                        float* __restrict__ out) {
    __shared__ float  srec[16*20*32];        // 40960 B: staged stroke records
    __shared__ float4 scol[16*20];           //  5120 B: staged colors
    __shared__ int    sidx[16*20];           //  1280 B: staged stroke ids
    int tt0 = threadIdx.x, lane = tt0 & 63, wq = tt0 >> 6;
    int x = blockIdx.x * 16 + ((wq & 1) << 3) + (lane & 7);   // wave = 8x8 pixel tile
    int y = blockIdx.y * 16 + ((wq >> 1) << 3) + (lane >> 3);
    int cy0 = (blockIdx.y * 16 * 51) >> 8;   // window origin (<=98)
    int cx0 = (blockIdx.x * 16 * 51) >> 8;

    // ---- stage cell idx lists, then records ----
    for (int s = tt0; s < 16*20; s += 256) {
        int c = s / 20, k = s - c * 20;
        int cellI = (cy0 + (c >> 2)) * HC + cx0 + (c & 3);
        sidx[s] = idcs[cellI * KK + k];
    }
    __syncthreads();
    for (int s = tt0; s < 16*20*8; s += 256) {   // 8 float4 per record
        int r = s >> 3, wd = s & 7;
        ((float4*)srec)[s] = ((const float4*)sdata)[sidx[r] * 8 + wd];
    }
    for (int s = tt0; s < 16*20; s += 256) scol[s] = ctab[sidx[s]];
    __syncthreads();

    const float df = 512.0f / 511.0f;        // linspace(0,512,512) step in fp32
    float p0 = (float)y * df;                // H-coordinate
    float p1 = (float)x * df;                // W-coordinate
    int cy = (y * 51) >> 8;                  // floor(y*102/512), exact vs fp32 ref
    int cx = (x * 51) >> 8;
    int lc = ((cy - cy0) << 2) + (cx - cx0); // local cell in the 4x4 window

    // jax.image.resize linear: half-pixel centers + edge-normalized == clamped bilinear
    const float sc = 102.0f / 512.0f;        // exact in fp32
    float iny = ((float)y + 0.5f) * sc - 0.5f;
    float inx = ((float)x + 0.5f) * sc - 0.5f;
    float y0f = floorf(iny), x0f = floorf(inx);
    float fy = iny - y0f, fx = inx - x0f;
    int y0 = min(max((int)y0f, 0), HC - 1);
    int y1 = min(max((int)y0f + 1, 0), HC - 1);
    int x0 = min(max((int)x0f, 0), HC - 1);
    int x1 = min(max((int)x0f + 1, 0), HC - 1);
    const float* w00 = wk + (y0 * HC + x0) * KK;
    const float* w01 = wk + (y0 * HC + x1) * KK;
    const float* w10 = wk + (y1 * HC + x0) * KK;
    const float* w11 = wk + (y1 * HC + x1) * KK;

    float m = -INFINITY, s = 0.0f;
    float a0 = 0.0f, a1 = 0.0f, a2 = 0.0f, wa = 0.0f;
    float D = INFINITY;

    #pragma unroll 4
    for (int k = 0; k < KK; ++k) {
        const float4* sp = (const float4*)(srec + (lc * 20 + k) * 32);
        float4 f0 = sp[0], f1 = sp[1], f2 = sp[2], f3 = sp[3], f4 = sp[4];
        float4 i0 = sp[5], i1 = sp[6], i2 = sp[7];
        float4 cw = scol[lc * 20 + k];
        float qx[10] = {f0.x, f0.z, f1.x, f1.z, f2.x, f2.z, f3.x, f3.z, f4.x, f4.z};
        float qy[10] = {f0.y, f0.w, f1.y, f1.w, f2.y, f2.w, f3.y, f3.w, f4.y, f4.w};
        float iv[9]  = {i0.x, i0.y, i0.z, i0.w, i1.x, i1.y, i1.z, i1.w, i2.x};
        float mink = INFINITY;
        #pragma unroll
        for (int sg = 0; sg < 9; ++sg) {
            float ax = qx[sg], ay = qy[sg];
            float bx = qx[sg+1] - ax, by = qy[sg+1] - ay;
            float pax = p0 - ax, pay = p1 - ay;
            float dot = bx * pax + by * pay;
            float tt = dot * iv[sg];
            tt = fminf(fmaxf(tt, 0.0f), 1.0f);
            float ccx = ax + tt * bx, ccy = ay + tt * by;
            float ddx = p0 - ccx, ddy = p1 - ccy;
            float d = ddx * ddx + ddy * ddy;
            mink = fminf(mink, d);
        }
        D = fminf(D, mink);
        float z = 100000.0f / (1e-8f + mink);    // IEEE div: exponent is rounding-sensitive
        float wkv = (1.0f - fy) * ((1.0f - fx) * w00[k] + fx * w01[k])
                  +          fy * ((1.0f - fx) * w10[k] + fx * w11[k]);
        // branchless online softmax (== subtract-max softmax, exp(0)==1 exactly)
        float nm  = fmaxf(m, z);
        float scl = __expf(m - nm);              // m=-inf first iter -> 0
        float e   = __expf(z - nm);
        s  = s  * scl + e;
        a0 = a0 * scl + cw.x * e;
        a1 = a1 * scl + cw.y * e;
        a2 = a2 * scl + cw.z * e;
        wa = wa * scl + wkv * e;
        m = nm;
    }
    float inv = 1.0f / s;
    float bs = wa * inv;
    float msk = 1.0f / (1.0f + __expf(-(bs - D)));   // sigmoid
    float o0 = a0 * inv * msk + (1.0f - msk) * 0.5f;
    float o1 = a1 * inv * msk + (1.0f - msk) * 0.5f;
    float o2 = a2 * inv * msk + (1.0f - msk) * 0.5f;
    int base = (y * 512 + x) * 3;
    out[base+0] = o0;
    out[base+1] = o1;
    out[base+2] = o2;
}

extern "C" void kernel_launch(void* const* d_in, const int* in_sizes, int n_in,
                              void* d_out, int out_size, void* d_ws, size_t ws_size,
                              hipStream_t stream) {
    const float* cs    = (const float*)d_in[0];  // curve_s (5000,2)
    const float* ce    = (const float*)d_in[1];  // curve_e (5000,2)
    const float* cc    = (const float*)d_in[2];  // curve_c (5000,2)
    const float* color = (const float*)d_in[3];  // color   (5000,3)
    const float* loc   = (const float*)d_in[4];  // location(5000,2)
    const float* width = (const float*)d_in[5];  // width   (5000,1)
    float* out = (float*)d_out;

    char* p = (char*)d_ws;
    float*  sdata    = (float*)p;                 p += NS * 32 * sizeof(float);       // 640000
    float4* ctab     = (float4*)p;                p += NS * sizeof(float4);           // 80000
    int*    idcs     = (int*)p;                   p += (size_t)HC*HC*KK*sizeof(int);  // 832320
    float*  wk       = (float*)p;                 p += (size_t)HC*HC*KK*sizeof(float);// 832320
    int*    binCntP  = (int*)p;                   p += NPB * NBIN*NBIN * sizeof(int); // 81920
    int*    binStart = (int*)p;                   p += 4112;                          // 1025 ints + pad
    float2* sxy      = (float2*)p;                p += NS * sizeof(float2);           // 40000
    int*    sid      = (int*)p;                   /* 20000 */

    prep_kernel   <<<NPB, 256, 0, stream>>>(cs, ce, cc, loc, color, width, sdata, ctab, binCntP);
    scatter_kernel<<<NPB, 256, 0, stream>>>(loc, binCntP, binStart, sxy, sid);
    topk_kernel   <<<(HC*HC)/4, 256, 0, stream>>>(loc, width, sxy, sid, binStart, idcs, wk);
    render_kernel <<<dim3(32, 32), 256, 0, stream>>>(sdata, ctab, idcs, wk, out);
}